// Round 11
// baseline (402.923 us; speedup 1.0000x reference)
//
#include <hip/hip_runtime.h>
#include <cstddef>
#include <cstdint>

#define N_NODES 10000
#define N_EDGES 160000

// ---- constants ----
#define RS8    0.35355339059327373f   // 1/sqrt(8)
#define RS32   0.17677669529663687f   // 1/sqrt(32)
#define RS96   0.10206207261596575f   // 1/sqrt(96)
#define RS128  0.08838834764831845f   // 1/sqrt(128)
#define RS3    0.5773502691896258f    // 1/sqrt(3)
#define SQ3_   1.7320508075688772f
#define SQ5_   2.23606797749979f
#define A_     0.18257418583505536f   // 1/sqrt(30)
#define B_     0.31622776601683794f   // 1/sqrt(10)
#define SILU_C_ 1.6765208f
#define CS_    0.3826834323650898f    // sin(pi/8)
#define CX_    0.9238795325112867f    // cos(pi/8)
#define QDEG   0.25f                  // 1/sqrt(16)

typedef __attribute__((ext_vector_type(8))) short bf16x8;
typedef __attribute__((ext_vector_type(4))) float f32x4;
typedef __attribute__((ext_vector_type(2))) float f32x2;

__device__ inline float bf2f(unsigned v) {
  union { unsigned u; float f; } c; c.u = v << 16; return c.f;
}
__device__ inline float bfhi(unsigned v) {   // float from HIGH 16 bits
  union { unsigned u; float f; } c; c.u = v & 0xffff0000u; return c.f;
}
__device__ inline unsigned short f2bf(float f) {
  union { float f; unsigned u; } c; c.f = f;
  unsigned r = c.u + 0x7fff + ((c.u >> 16) & 1);
  return (unsigned short)(r >> 16);
}
// packed f32x2 -> 2xbf16 in one instruction (RNE, same as f2bf)
__device__ inline unsigned cvtpk2bf(float a, float b) {
  unsigned r;
  asm("v_cvt_pk_bf16_f32 %0, %1, %2" : "=v"(r) : "v"(a), "v"(b));
  return r;
}

// build fc1p (fc1 64x320 f32 -> bf16 MFMA B-fragment order, PRE-SCALED by
// K=0.125 — exact in bf16)
// + (split) transpose lin2/sc weights (wt, 18432 f)
// + transpose lin1 weights + fc0 (l1t, 5632 f)
// + zero the scan-done flag
// + grid-stride histogram of edge_dst into counts (counts pre-zeroed by memset).
__global__ void k_init(const int* __restrict__ edst, int* __restrict__ counts,
                       const float* __restrict__ fc1,
                       unsigned short* __restrict__ fc1p,
                       const float* __restrict__ w0, const float* __restrict__ sc_w0,
                       const float* __restrict__ w1, const float* __restrict__ w2,
                       const float* __restrict__ sc_w1, float* __restrict__ wt,
                       const float* __restrict__ l1_w0, const float* __restrict__ l1_w1,
                       const float* __restrict__ fc0, float* __restrict__ l1t,
                       int* __restrict__ flag) {
  int i = blockIdx.x * blockDim.x + threadIdx.x;
  int stride = gridDim.x * blockDim.x;
  if (i == 0 && flag) *flag = 0;
  if (i < 20480) {
    int j = i & 7, q = (i >> 3) & 3, n = (i >> 5) & 15, kq = (i >> 9) & 1, t = i >> 10;
    int k = kq * 32 + q * 8 + j;
    fc1p[i] = f2bf(fc1[k * 320 + t * 16 + n] * 0.125f);
  }
  if (wt && i >= 20480 && i < 38912) {
    int j = i - 20480;
    float* w0t  = wt;
    float* sw0t = wt + 6144;
    float* w1t  = wt + 10240;
    float* w2t  = wt + 14336;
    float* sw1t = wt + 17408;
    if (j < 6144) {
      int u = j >> 6, oc = j & 63; w0t[oc * 96 + u] = w0[u * 64 + oc];
    } else if (j < 10240) {
      int q = j - 6144; int u = q >> 6, oc = q & 63; sw0t[oc * 64 + u] = sc_w0[u * 64 + oc];
    } else if (j < 14336) {
      int q = j - 10240; int u = q >> 5, v = q & 31; w1t[v * 128 + u] = w1[u * 32 + v];
    } else if (j < 17408) {
      int q = j - 14336; int u = q >> 5, v = q & 31; w2t[v * 96 + u] = w2[u * 32 + v];
    } else {
      int q = j - 17408; int u = q >> 5, v = q & 31; sw1t[v * 32 + u] = sc_w1[u * 32 + v];
    }
  }
  if (l1t && i >= 38912 && i < 44544) {
    int j = i - 38912;
    if (j < 4096) {
      int c = j >> 6, u = j & 63;
      l1t[c * 64 + u] = l1_w0[u * 64 + c];
    } else if (j < 5120) {
      int q = j - 4096; int v = q >> 5, u = q & 31;
      l1t[4096 + v * 32 + u] = l1_w1[u * 32 + v];
    } else {
      int q = j - 5120; int k = q >> 3, m = q & 7;
      l1t[5120 + k * 8 + m] = fc0[m * 64 + k];
    }
  }
  for (int e = i; e < N_EDGES; e += stride) atomicAdd(&counts[edst[e]], 1);
}

// scan body (block 0 of k_big): exclusive scan of counts -> offs/cur; degree
// histogram + descending-degree exclusive scan -> dcur. Releases `flag` when
// done (device-scope) so the in-kernel perm blocks may proceed.
__device__ void scan_body(char* raw, const int* __restrict__ counts,
                          int* __restrict__ offs, int* __restrict__ cur,
                          int* __restrict__ dcur, int* __restrict__ flag) {
  int* ps = (int*)raw;
  int* dbin = ps + 256;
  int t = threadIdx.x;
  dbin[t] = 0;
  int base = t * 40;
  int sum = 0;
  for (int i = 0; i < 40; ++i) {
    int idx = base + i;
    if (idx < N_NODES) sum += counts[idx];
  }
  ps[t] = sum;
  __syncthreads();
  for (int off = 1; off < 256; off <<= 1) {
    int v = (t >= off) ? ps[t - off] : 0;
    __syncthreads();
    ps[t] += v;
    __syncthreads();
  }
  int run = (t == 0) ? 0 : ps[t - 1];
  for (int i = 0; i < 40; ++i) {
    int idx = base + i;
    if (idx < N_NODES) {
      int c = counts[idx];
      offs[idx] = run; cur[idx] = run;
      run += c;
      atomicAdd(&dbin[c < 255 ? c : 255], 1);
    }
  }
  __syncthreads();
  int rb = 255 - t;
  int v = dbin[rb];
  __syncthreads();
  ps[t] = v;
  __syncthreads();
  for (int off = 1; off < 256; off <<= 1) {
    int u = (t >= off) ? ps[t - off] : 0;
    __syncthreads();
    ps[t] += u;
    __syncthreads();
  }
  dcur[rb] = ps[t] - v;
  __syncthreads();
  __threadfence();
  if (t == 0)
    __hip_atomic_store(flag, 1, __ATOMIC_RELEASE, __HIP_MEMORY_SCOPE_AGENT);
}

// perm body (blocks [3126,3751) of k_big, dispatched LAST): spins on the
// scan-done flag (block 0 is always resident/progressing -> no deadlock),
// then per edge computes sorted position p and scatter-writes ed2 (stride
// 12 f = 48 B): [0..8]=SH, [9]=src, [10]=orig idx, [11]=pad. Also the node
// scatter (degree-desc rank -> order/obeg/ocnt).
__device__ void perm_body(char* raw, int pblk,
    const int* __restrict__ edst, int* __restrict__ cur,
    const int* __restrict__ counts, const int* __restrict__ offs,
    int* __restrict__ dcur, int* __restrict__ order,
    int* __restrict__ obeg, int* __restrict__ ocnt,
    const float* __restrict__ eattr,
    const int* __restrict__ esrc, float* __restrict__ ed2,
    int* __restrict__ flag) {
  float* sh_ea = (float*)raw;     // 9216 B of the 11328-B shared buffer
  int t = threadIdx.x;
  if (t == 0) {
    while (__hip_atomic_load(flag, __ATOMIC_ACQUIRE, __HIP_MEMORY_SCOPE_AGENT) == 0)
      __builtin_amdgcn_s_sleep(8);
  }
  __syncthreads();
  __threadfence();
  int eb = pblk * 256;
  int e = eb + t;
  for (int i = t; i < 2304; i += 256) sh_ea[i] = eattr[(size_t)eb * 9 + i];
  __syncthreads();
  int d = edst[e];
  int p = atomicAdd(&cur[d], 1);
  const float* ea = sh_ea + t * 9;
  float4 r0 = {ea[0], ea[1], ea[2], ea[3]};
  float4 r1 = {ea[4], ea[5], ea[6], ea[7]};
  float4 r2 = {ea[8], __int_as_float(esrc[e]), __int_as_float(e), 0.f};
  float4* dst = (float4*)(ed2 + (size_t)p * 12);
  dst[0] = r0; dst[1] = r1; dst[2] = r2;
  if (e < N_NODES) {
    int c = counts[e];
    int b = c < 255 ? c : 255;
    int q = atomicAdd(&dcur[b], 1);
    order[q] = e; obeg[q] = offs[e]; ocnt[q] = c;
  }
}

// standalone perm kernel (small-ws fallback path only)
__global__ __launch_bounds__(256) void k_perm(
    const int* __restrict__ edst, int* __restrict__ cur,
    const int* __restrict__ counts, const int* __restrict__ offs,
    int* __restrict__ dcur, int* __restrict__ order,
    int* __restrict__ obeg, int* __restrict__ ocnt,
    const float* __restrict__ eattr,
    const int* __restrict__ esrc, float* __restrict__ ed2) {
  __shared__ __align__(16) float sh_ea[256 * 9];
  int t = threadIdx.x;
  int eb = blockIdx.x * 256;
  int e = eb + t;
  for (int i = t; i < 2304; i += 256) sh_ea[i] = eattr[(size_t)eb * 9 + i];
  __syncthreads();
  int d = edst[e];
  int p = atomicAdd(&cur[d], 1);
  const float* ea = sh_ea + t * 9;
  float4 r0 = {ea[0], ea[1], ea[2], ea[3]};
  float4 r1 = {ea[4], ea[5], ea[6], ea[7]};
  float4 r2 = {ea[8], __int_as_float(esrc[e]), __int_as_float(e), 0.f};
  float4* dst = (float4*)(ed2 + (size_t)p * 12);
  dst[0] = r0; dst[1] = r1; dst[2] = r2;
  if (e < N_NODES) {
    int c = counts[e];
    int b = c < 255 ? c : 255;
    int q = atomicAdd(&dcur[b], 1);
    order[q] = e; obeg[q] = offs[e]; ocnt[q] = c;
  }
}

__device__ inline f32x4 wtile(const unsigned short* __restrict__ fc1p,
                              bf16x8 a0, bf16x8 a1, int mrow, int quad, int t) {
  f32x4 acc = {0.f, 0.f, 0.f, 0.f};
  bf16x8 b0 = *(const bf16x8*)(fc1p + ((size_t)((t * 2 + 0) * 16 + mrow) * 4 + quad) * 8);
  bf16x8 b1 = *(const bf16x8*)(fc1p + ((size_t)((t * 2 + 1) * 16 + mrow) * 4 + quad) * 8);
  acc = __builtin_amdgcn_mfma_f32_16x16x32_bf16(b0, a0, acc, 0, 0, 0);
  acc = __builtin_amdgcn_mfma_f32_16x16x32_bf16(b1, a1, acc, 0, 0, 0);
  return acc;
}

struct WgemmShared {
  __align__(16) float ele[64][8];
  __align__(16) unsigned short h[64 * 72];   // 72-stride pad
};

// STREAMING MFMA radial GEMM: 64 edges/block in ORIGINAL edge order,
// writes packed wbuf (640 B/edge). fc1p pre-scaled by K; pack via
// v_cvt_pk_bf16_f32. PK=true: h-stage uses fc0t rows (v_pk_fma).
template <bool PK>
__device__ void w_gemm_body(WgemmShared& sh, int blk,
    const float* __restrict__ eleg, const float* __restrict__ fc0,
    const float* __restrict__ fc0t,
    const unsigned short* __restrict__ fc1p, unsigned short* __restrict__ wout) {
  int t = threadIdx.x;
  int eb = blk * 64;
  if (t < 128) {
    int e = t >> 1, hh = t & 1;
    ((float4*)&sh.ele[e][0])[hh] =
        *(const float4*)(eleg + (size_t)(eb + e) * 8 + hh * 4);
  }
  __syncthreads();
  #pragma unroll
  for (int ii = 0; ii < 16; ++ii) {
    int idx = t + ii * 256;
    int e = idx >> 6, k = idx & 63;
    float acc;
    if constexpr (PK) {
      f32x2 a2 = {0.f, 0.f};
      const f32x2* er = (const f32x2*)&sh.ele[e][0];
      const f32x2* fr = (const f32x2*)(fc0t + k * 8);
      #pragma unroll
      for (int m = 0; m < 4; ++m) a2 += er[m] * fr[m];
      acc = a2.x + a2.y;
    } else {
      acc = 0.f;
      #pragma unroll
      for (int m = 0; m < 8; ++m) acc += sh.ele[e][m] * fc0[m * 64 + k];
    }
    acc *= RS8;
    float hv = SILU_C_ * acc / (1.f + __expf(-acc));
    sh.h[e * 72 + k] = f2bf(hv);
  }
  __syncthreads();

  int wv = t >> 6, lane = t & 63;
  int m0 = wv * 16;
  int mrow = lane & 15, quad = lane >> 4;
  bf16x8 a0 = *(const bf16x8*)(sh.h + (m0 + mrow) * 72 + quad * 8);
  bf16x8 a1 = *(const bf16x8*)(sh.h + (m0 + mrow) * 72 + 32 + quad * 8);
  char* wbase = (char*)wout + (size_t)(eb + m0 + mrow) * 640;
  #pragma unroll
  for (int tt = 0; tt < 4; ++tt) {
    f32x4 Av = wtile(fc1p, a0, a1, mrow, quad, tt);
    f32x4 Bv = wtile(fc1p, a0, a1, mrow, quad, tt + 4);
    uint4 st;
    st.x = cvtpk2bf(Av[0], Bv[0]);
    st.y = cvtpk2bf(Av[1], Bv[1]);
    st.z = cvtpk2bf(Av[2], Bv[2]);
    st.w = cvtpk2bf(Av[3], Bv[3]);
    *(uint4*)(wbase + 64 * tt + 16 * quad) = st;
  }
  #pragma unroll
  for (int tt = 8; tt < 12; ++tt) {
    f32x4 Cv = wtile(fc1p, a0, a1, mrow, quad, tt);
    uint2 st;
    st.x = cvtpk2bf(Cv[0], Cv[1]);
    st.y = cvtpk2bf(Cv[2], Cv[3]);
    *(uint2*)(wbase + 256 + 32 * (tt - 8) + 8 * quad) = st;
  }
  #pragma unroll
  for (int tt = 12; tt < 14; ++tt) {
    f32x4 Dv = wtile(fc1p, a0, a1, mrow, quad, tt);
    f32x4 Ev = wtile(fc1p, a0, a1, mrow, quad, tt + 2);
    f32x4 Fv = wtile(fc1p, a0, a1, mrow, quad, tt + 4);
    f32x4 Gv = wtile(fc1p, a0, a1, mrow, quad, tt + 6);
    char* db = wbase + 384 + 128 * (tt - 12) + 32 * quad;
    uint4 s0, s1;
    s0.x = cvtpk2bf(Dv[0], Ev[0]); s0.y = cvtpk2bf(Fv[0], Gv[0]);
    s0.z = cvtpk2bf(Dv[1], Ev[1]); s0.w = cvtpk2bf(Fv[1], Gv[1]);
    s1.x = cvtpk2bf(Dv[2], Ev[2]); s1.y = cvtpk2bf(Fv[2], Gv[2]);
    s1.z = cvtpk2bf(Dv[3], Ev[3]); s1.w = cvtpk2bf(Fv[3], Gv[3]);
    *(uint4*)(db) = s0;
    *(uint4*)(db + 16) = s1;
  }
}

// node_pre (split mode): k_out-style batched lin1, pk-packed dots.
#define NBK_PRE 16
__device__ void node_pre_body2(float* sh, int blk,
    const float* __restrict__ xin, const float* __restrict__ attr,
    const float* __restrict__ l1w0t, const float* __restrict__ l1w1t,
    float* __restrict__ y) {
  int t = threadIdx.x;
  int n0 = blk * NBK_PRE;
  for (int i = t; i < NBK_PRE * 160; i += 256) {
    int n = i / 160, c = i - n * 160;
    float v = xin[(size_t)(n0 + n) * 160 + c];
    int dst;
    if (c < 64) dst = c;
    else { int q = c - 64; int u = q / 3; int ii = q - u * 3; dst = 64 + ii * 32 + u; }
    sh[n * 176 + dst] = v;
  }
  if (t < NBK_PRE) sh[2816 + t] = attr[n0 + t];
  __syncthreads();
  if (t < 64) {
    const float4* wr = (const float4*)(l1w0t + t * 64);
    f32x2 a2[NBK_PRE];
    #pragma unroll
    for (int n = 0; n < NBK_PRE; ++n) a2[n] = (f32x2){0.f, 0.f};
    #pragma unroll 4
    for (int c4 = 0; c4 < 16; ++c4) {
      float4 wv = wr[c4];
      f32x2 wlo = {wv.x, wv.y}, whi = {wv.z, wv.w};
      #pragma unroll
      for (int n = 0; n < NBK_PRE; ++n) {
        float4 xv = *(const float4*)(sh + n * 176 + 4 * c4);
        f32x2 xlo = {xv.x, xv.y}, xhi = {xv.z, xv.w};
        a2[n] += xlo * wlo;
        a2[n] += xhi * whi;
      }
    }
    #pragma unroll
    for (int n = 0; n < NBK_PRE; ++n)
      y[(size_t)(n0 + n) * 192 + t] = (a2[n].x + a2[n].y) * sh[2816 + n] * 0.125f;
  } else if (t < 160) {
    int q = t - 64, v = q / 3, ii = q - v * 3;
    const float4* wr = (const float4*)(l1w1t + v * 32);
    f32x2 a2[NBK_PRE];
    #pragma unroll
    for (int n = 0; n < NBK_PRE; ++n) a2[n] = (f32x2){0.f, 0.f};
    #pragma unroll 2
    for (int c4 = 0; c4 < 8; ++c4) {
      float4 wv = wr[c4];
      f32x2 wlo = {wv.x, wv.y}, whi = {wv.z, wv.w};
      #pragma unroll
      for (int n = 0; n < NBK_PRE; ++n) {
        float4 xv = *(const float4*)(sh + n * 176 + 64 + ii * 32 + 4 * c4);
        f32x2 xlo = {xv.x, xv.y}, xhi = {xv.z, xv.w};
        a2[n] += xlo * wlo;
        a2[n] += xhi * whi;
      }
    }
    #pragma unroll
    for (int n = 0; n < NBK_PRE; ++n) {
      float r = (a2[n].x + a2[n].y) * sh[2816 + n] * RS32;
      float* yr = y + (size_t)(n0 + n) * 192 + 64 + v * 4;
      yr[ii] = r;
      if (ii == 2) yr[3] = 0.f;
    }
  }
}

// OLD node_pre (fallback only)
__device__ void node_pre_body(int blk,
    const float* __restrict__ xin, const float* __restrict__ attr,
    const float* __restrict__ l1_w0, const float* __restrict__ l1_w1,
    float* __restrict__ y) {
  int idx = blk * 256 + threadIdx.x;
  int n = idx / 160, c = idx - n * 160;
  const float* xr = xin + (size_t)n * 160;
  float a = attr[n];
  if (c < 64) {
    float y_ = 0.f;
    #pragma unroll 8
    for (int u = 0; u < 64; ++u) y_ += xr[u] * l1_w0[u * 64 + c];
    y[(size_t)n * 192 + c] = y_ * a * 0.125f;
  } else {
    int t = c - 64; int v = t / 3, i = t - v * 3;
    float y_ = 0.f;
    #pragma unroll 8
    for (int u = 0; u < 32; ++u) y_ += xr[64 + u * 3 + i] * l1_w1[u * 32 + v];
    y[(size_t)n * 192 + 64 + v * 4 + i] = y_ * a * RS32;
    if (i == 2) y[(size_t)n * 192 + 64 + v * 4 + 3] = 0.f;
  }
}

// big fused mid-stage (launched right after k_init):
// block 0            = scan (releases flag)
// blocks [1,2501)    = w_gemm (original edge order)
// PRE2=true : [2501,3126) = node_pre_body2; [3126,3751) = perm (spins on flag)
// PRE2=false: [2501,8751) = old node_pre (perm runs standalone)
template <bool PRE2>
__global__ __launch_bounds__(256) void k_big(
    const float* __restrict__ eleg, const float* __restrict__ fc0,
    const unsigned short* __restrict__ fc1p, unsigned short* __restrict__ wout,
    const float* __restrict__ xin, const float* __restrict__ attr,
    const float* __restrict__ l1_w0, const float* __restrict__ l1_w1,
    const float* __restrict__ l1w0t, const float* __restrict__ l1w1t,
    const float* __restrict__ fc0t, float* __restrict__ y,
    const int* __restrict__ counts, int* __restrict__ offs,
    int* __restrict__ cur, int* __restrict__ dcur,
    const int* __restrict__ edst, int* __restrict__ order,
    int* __restrict__ obeg, int* __restrict__ ocnt,
    const float* __restrict__ eattr, const int* __restrict__ esrc,
    float* __restrict__ ed2, int* __restrict__ flag) {
  __shared__ __align__(16) char shraw[11328];
  if (blockIdx.x == 0) {
    scan_body(shraw, counts, offs, cur, dcur, flag);
  } else if (blockIdx.x <= 2500) {
    w_gemm_body<PRE2>(*(WgemmShared*)shraw, blockIdx.x - 1, eleg, fc0, fc0t, fc1p, wout);
  } else if (PRE2) {
    if (blockIdx.x < 3126) {
      node_pre_body2((float*)shraw, blockIdx.x - 2501, xin, attr, l1w0t, l1w1t, y);
    } else {
      perm_body(shraw, blockIdx.x - 3126, edst, cur, counts, offs, dcur,
                order, obeg, ocnt, eattr, esrc, ed2, flag);
    }
  } else {
    node_pre_body(blockIdx.x - 2501, xin, attr, l1_w0, l1_w1, y);
  }
}

// node_agg:
// EPI=true : 2000 blocks x 5 waves (320 thr), ONE NODE PER WAVE in
//            degree-desc order (rank = blk*5+wid). R9 scalarized loop
//            (ed2 s_load, SALU bases). Bank-padded component-major LDS
//            (node stride 1152, 5 nodes = 23.1 KB); SINGLE-PASS epilogue:
//            thread t owns channel t (320==320), weight float4 reused
//            over 5 nodes, pk-packed dots.
// EPI=false: 2500x4x256 fallback with original fused epilogue.
#define WREG 960
template <bool EPI>
__global__ __launch_bounds__(320) void node_agg(
    const float* __restrict__ y, const float* __restrict__ xin,
    const float* __restrict__ attr, const float* __restrict__ ed2,
    const unsigned short* __restrict__ wbuf,
    const int* __restrict__ order, const int* __restrict__ obeg,
    const int* __restrict__ ocnt,
    const float* __restrict__ sc_w0, const float* __restrict__ sc_w1,
    const float* __restrict__ w0, const float* __restrict__ w1,
    const float* __restrict__ w2, float* __restrict__ out,
    const float* __restrict__ wt) {
  int tid = threadIdx.x, wid = tid >> 6, lane = tid & 63, l31 = lane & 31;
  int gw = blockIdx.x * (EPI ? 5 : 4) + wid;
  // fixed per-lane byte offsets (loop-invariant)
  int voY  = 4 * lane;           // y scalar block
  int voX  = 256 + 16 * l31;     // y vector float4 {x0,x1,x2,0}
  int voAB = 4 * lane;           // wbuf AB
  int voC  = 256 + 2 * lane;     // wbuf C
  int voDG = 384 + 8 * l31;      // wbuf DEFG

#define E_LOAD(S, idx)                                                         \
  if ((idx) < cnt) {                                                           \
    int ro_ = __builtin_amdgcn_readfirstlane(beg + (idx));                     \
    const float4* ep = (const float4*)(ed2 + (size_t)ro_ * 12);                \
    PE0##S = ep[0]; PE1##S = ep[1]; PE2##S = ep[2];                            \
  }
#define V_LOAD(S, idx)                                                         \
  if ((idx) < cnt) {                                                           \
    int srcn = __builtin_amdgcn_readfirstlane(__float_as_int(PE2##S.y));       \
    int eorg = __builtin_amdgcn_readfirstlane(__float_as_int(PE2##S.z));       \
    const char* yb = (const char*)y + (size_t)srcn * 768;                      \
    Y##S = *(const float*)(yb + voY);                                          \
    X##S = *(const f32x4*)(yb + voX);                                          \
    const char* wb = (const char*)wbuf + (size_t)eorg * 640;                   \
    AB##S = *(const unsigned*)(wb + voAB);                                     \
    Cw##S = *(const unsigned short*)(wb + voC);                                \
    DG##S = *(const uint2*)(wb + voDG);                                        \
  }
#define COMPUTE(S)                                                             \
  {                                                                            \
    float e0 = PE0##S.x, ey = PE0##S.y, ez = PE0##S.z, ex = PE0##S.w;          \
    float q0 = PE1##S.x, q1 = PE1##S.y, q2 = PE1##S.z, q3 = PE1##S.w;          \
    float q4 = PE2##S.x;                                                       \
    float Yv = Y##S, x0 = X##S.x, x1 = X##S.y, x2 = X##S.z;                    \
    float vA = bf2f(AB##S), vB = bfhi(AB##S), vC = bf2f(Cw##S);                \
    float vD = bf2f(DG##S.x), vE = bfhi(DG##S.x);                              \
    float vF = bf2f(DG##S.y), vG = bfhi(DG##S.y);                              \
    aK0 += Yv * e0 * vA;                                                       \
    float tB = Yv * vB; aK2x += tB * ey; aK2y += tB * ez; aK2z += tB * ex;     \
    float tC = Yv * vC;                                                        \
    aK5a += tC * q0; aK5b += tC * q1; aK5c += tC * q2;                         \
    aK5d += tC * q3; aK5e += tC * q4;                                          \
    float t1 = x0 * ey + x1 * ez + x2 * ex; aK1 += (RS3 * vE) * t1;            \
    float s3 = e0 * vD; aK3x += x0 * s3; aK3y += x1 * s3; aK3z += x2 * s3;     \
    float s4 = SQ3_ * vG;                                                      \
    aK4x += s4 * (B_ * (x2 * q0 + x1 * q1 - x0 * q4) - A_ * x0 * q2);          \
    aK4y += s4 * (B_ * (x0 * q1 + x2 * q3) + 2.f * A_ * x1 * q2);              \
    aK4z += s4 * (B_ * (x0 * q0 + x1 * q3 + x2 * q4) - A_ * x2 * q2);          \
    float s6 = SQ5_ * vF;                                                      \
    aK6a += s6 * (-B_ * (x0 * ex + x2 * ey));                                  \
    aK6b += s6 * (-B_ * (x0 * ez + x1 * ey));                                  \
    aK6c += s6 * ( A_ * (x0 * ey + x2 * ex - 2.f * x1 * ez));                  \
    aK6d += s6 * (-B_ * (x1 * ex + x2 * ez));                                  \
    aK6e += s6 * ( B_ * (x0 * ey - x2 * ex));                                  \
  }
#define LWAIT __asm__ volatile("s_waitcnt lgkmcnt(0)" ::: "memory")

  int n = order[gw], beg = obeg[gw], cnt = ocnt[gw];

  float aK0 = 0.f, aK2x = 0.f, aK2y = 0.f, aK2z = 0.f;
  float aK5a = 0.f, aK5b = 0.f, aK5c = 0.f, aK5d = 0.f, aK5e = 0.f;
  float aK1 = 0.f, aK3x = 0.f, aK3y = 0.f, aK3z = 0.f;
  float aK4x = 0.f, aK4y = 0.f, aK4z = 0.f;
  float aK6a = 0.f, aK6b = 0.f, aK6c = 0.f, aK6d = 0.f, aK6e = 0.f;

  float4 PE0a, PE1a, PE2a, PE0b, PE1b, PE2b;
  float Ya, Yb; f32x4 Xa, Xb;
  unsigned ABa, ABb; unsigned short Cwa, Cwb;
  uint2 DGa, DGb;

  E_LOAD(a, 0)
  E_LOAD(b, 1)
  V_LOAD(a, 0)

  int i = 0;
  while (i < cnt) {
    V_LOAD(b, i + 1)
    COMPUTE(a)
    E_LOAD(a, i + 2)
    ++i; if (i >= cnt) break;
    V_LOAD(a, i + 1)
    COMPUTE(b)
    E_LOAD(b, i + 2)
    ++i;
  }

  if constexpr (EPI) {
    // per-node layout (floats, node stride 1152):
    //   R[0,984)  bank-padded: m0@0 (96), m1@96 stride 132, m2@488 stride 100
    //   xin[984,1144), pad[1144,1152)
    // meta: attr @5760+wid, nid @int 5768+wid
    __shared__ __align__(16) float sepi[5 * 1152 + 16];
    float* R = sepi + wid * 1152;
    R[lane]        = aK0  * QDEG;   // m0 u=lane          (k0)
    R[96 + lane]   = aK2x * QDEG;   // m1 ii=0 u=lane     (k2)
    R[228 + lane]  = aK2y * QDEG;   // m1 ii=1
    R[360 + lane]  = aK2z * QDEG;   // m1 ii=2
    R[488 + lane]  = aK5a * QDEG;   // m2 kk=0 u=lane     (k5)
    R[588 + lane]  = aK5b * QDEG;
    R[688 + lane]  = aK5c * QDEG;
    R[788 + lane]  = aK5d * QDEG;
    R[888 + lane]  = aK5e * QDEG;
    if (lane < 32) {
      R[64 + lane]   = aK1  * QDEG; // m0 u=64+lane       (k1)
      R[160 + lane]  = aK3x * QDEG; // m1 ii=0 u=64+lane  (k3)
      R[292 + lane]  = aK3y * QDEG;
      R[424 + lane]  = aK3z * QDEG;
      R[192 + lane]  = aK4x * QDEG; // m1 ii=0 u=96+lane  (k4)
      R[324 + lane]  = aK4y * QDEG;
      R[456 + lane]  = aK4z * QDEG;
      R[552 + lane]  = aK6a * QDEG; // m2 kk=0 u=64+lane  (k6)
      R[652 + lane]  = aK6b * QDEG;
      R[752 + lane]  = aK6c * QDEG;
      R[852 + lane]  = aK6d * QDEG;
      R[952 + lane]  = aK6e * QDEG;
    }
    if (lane < 40)
      *(float4*)(sepi + wid * 1152 + 984 + 4 * lane) =
          *(const float4*)(xin + (size_t)n * 160 + 4 * lane);
    if (lane == 40) sepi[5760 + wid] = attr[n];
    if (lane == 41) ((int*)sepi)[5768 + wid] = n;
    __syncthreads();
    const float* w0t  = wt;
    const float* sw0t = wt + 6144;
    const float* w1t  = wt + 10240;
    const float* w2t  = wt + 14336;
    const float* sw1t = wt + 17408;
    int ch = tid;  // 320 threads == 320 channels, single pass
    f32x2 a2[5];
    float accs[5] = {0.f, 0.f, 0.f, 0.f, 0.f};
    f32x2 s2[5];
    #pragma unroll
    for (int k = 0; k < 5; ++k) { a2[k] = (f32x2){0.f, 0.f}; s2[k] = (f32x2){0.f, 0.f}; }
    if (ch < 64) {
      const float4* wr  = (const float4*)(w0t + ch * 96);
      const float4* swr = (const float4*)(sw0t + ch * 64);
      #pragma unroll 4
      for (int c = 0; c < 24; ++c) {
        float4 wv = wr[c];
        f32x2 wlo = {wv.x, wv.y}, whi = {wv.z, wv.w};
        #pragma unroll
        for (int k = 0; k < 5; ++k) {
          float4 rv = *(const float4*)(sepi + k * 1152 + 4 * c);
          f32x2 rlo = {rv.x, rv.y}, rhi = {rv.z, rv.w};
          a2[k] += rlo * wlo;
          a2[k] += rhi * whi;
        }
      }
      #pragma unroll 4
      for (int c = 0; c < 16; ++c) {
        float4 wv = swr[c];
        f32x2 wlo = {wv.x, wv.y}, whi = {wv.z, wv.w};
        #pragma unroll
        for (int k = 0; k < 5; ++k) {
          float4 xv = *(const float4*)(sepi + k * 1152 + 984 + 4 * c);
          f32x2 xlo = {xv.x, xv.y}, xhi = {xv.z, xv.w};
          s2[k] += xlo * wlo;
          s2[k] += xhi * whi;
        }
      }
      #pragma unroll
      for (int k = 0; k < 5; ++k) {
        float a = sepi[5760 + k]; int nid = ((const int*)sepi)[5768 + k];
        float o = a2[k].x + a2[k].y, sv = s2[k].x + s2[k].y;
        out[(size_t)nid * 320 + ch] =
            CS_ * (sv * a * 0.125f) + CX_ * (o * a * RS96);
      }
    } else if (ch < 160) {
      int q = ch - 64, v = q / 3, ii = q - v * 3;
      const float4* wr = (const float4*)(w1t + v * 128);
      #pragma unroll 4
      for (int c = 0; c < 32; ++c) {
        float4 wv = wr[c];
        f32x2 wlo = {wv.x, wv.y}, whi = {wv.z, wv.w};
        #pragma unroll
        for (int k = 0; k < 5; ++k) {
          float4 rv = *(const float4*)(sepi + k * 1152 + 96 + ii * 132 + 4 * c);
          f32x2 rlo = {rv.x, rv.y}, rhi = {rv.z, rv.w};
          a2[k] += rlo * wlo;
          a2[k] += rhi * whi;
        }
      }
      for (int u = 0; u < 32; ++u) {
        float wv = sw1t[v * 32 + u];
        #pragma unroll
        for (int k = 0; k < 5; ++k)
          accs[k] += sepi[k * 1152 + 984 + 64 + 3 * u + ii] * wv;
      }
      #pragma unroll
      for (int k = 0; k < 5; ++k) {
        float a = sepi[5760 + k]; int nid = ((const int*)sepi)[5768 + k];
        float o = a2[k].x + a2[k].y;
        out[(size_t)nid * 320 + ch] =
            CS_ * (accs[k] * a * RS32) + CX_ * (o * a * RS128);
      }
    } else {
      int q = ch - 160, v = q / 5, kk = q - v * 5;
      const float4* wr = (const float4*)(w2t + v * 96);
      #pragma unroll 4
      for (int c = 0; c < 24; ++c) {
        float4 wv = wr[c];
        f32x2 wlo = {wv.x, wv.y}, whi = {wv.z, wv.w};
        #pragma unroll
        for (int k = 0; k < 5; ++k) {
          float4 rv = *(const float4*)(sepi + k * 1152 + 488 + kk * 100 + 4 * c);
          f32x2 rlo = {rv.x, rv.y}, rhi = {rv.z, rv.w};
          a2[k] += rlo * wlo;
          a2[k] += rhi * whi;
        }
      }
      #pragma unroll
      for (int k = 0; k < 5; ++k) {
        float a = sepi[5760 + k]; int nid = ((const int*)sepi)[5768 + k];
        float o = a2[k].x + a2[k].y;
        out[(size_t)nid * 320 + ch] = o * a * RS96;
      }
    }
  } else {
    // fallback: original fused epilogue (256-thread launch)
    __shared__ __align__(16) float smem[4 * WREG];
    float* R = smem + wid * WREG;
    R[lane]            = aK0  * QDEG;
    R[96 + 3 * lane]   = aK2x * QDEG;
    R[97 + 3 * lane]   = aK2y * QDEG;
    R[98 + 3 * lane]   = aK2z * QDEG;
    R[480 + 5 * lane]  = aK5a * QDEG;
    R[481 + 5 * lane]  = aK5b * QDEG;
    R[482 + 5 * lane]  = aK5c * QDEG;
    R[483 + 5 * lane]  = aK5d * QDEG;
    R[484 + 5 * lane]  = aK5e * QDEG;
    if (lane < 32) {
      R[64 + lane]       = aK1  * QDEG;
      R[288 + 3 * lane]  = aK3x * QDEG;
      R[289 + 3 * lane]  = aK3y * QDEG;
      R[290 + 3 * lane]  = aK3z * QDEG;
      R[384 + 3 * lane]  = aK4x * QDEG;
      R[385 + 3 * lane]  = aK4y * QDEG;
      R[386 + 3 * lane]  = aK4z * QDEG;
      R[800 + 5 * lane]  = aK6a * QDEG;
      R[801 + 5 * lane]  = aK6b * QDEG;
      R[802 + 5 * lane]  = aK6c * QDEG;
      R[803 + 5 * lane]  = aK6d * QDEG;
      R[804 + 5 * lane]  = aK6e * QDEG;
    }
    LWAIT;
    float a = attr[n];
    const float* xr = xin + (size_t)n * 160;
    float* orow = out + (size_t)n * 320;
    #pragma unroll
    for (int jo = 0; jo < 5; ++jo) {
      int oc = lane + 64 * jo;
      float res;
      if (oc < 64) {
        float o = 0.f, sv = 0.f;
        #pragma unroll 8
        for (int u = 0; u < 96; ++u) o += R[u] * w0[u * 64 + oc];
        #pragma unroll 8
        for (int u = 0; u < 64; ++u) sv += xr[u] * sc_w0[u * 64 + oc];
        res = CS_ * (sv * a * 0.125f) + CX_ * (o * a * RS96);
      } else if (oc < 160) {
        int t2 = oc - 64, v = t2 / 3, ii = t2 - v * 3;
        float o = 0.f, sv = 0.f;
        #pragma unroll 8
        for (int u = 0; u < 128; ++u) o += R[96 + u * 3 + ii] * w1[u * 32 + v];
        #pragma unroll 8
        for (int u = 0; u < 32; ++u) sv += xr[64 + u * 3 + ii] * sc_w1[u * 32 + v];
        res = CS_ * (sv * a * RS32) + CX_ * (o * a * RS128);
      } else {
        int t2 = oc - 160, v = t2 / 5, kk = t2 - v * 5;
        float o = 0.f;
        #pragma unroll 8
        for (int u = 0; u < 96; ++u) o += R[480 + u * 5 + kk] * w2[u * 32 + v];
        res = o * a * RS96;
      }
      orow[oc] = res;
    }
  }
#undef E_LOAD
#undef V_LOAD
#undef COMPUTE
#undef LWAIT
}

extern "C" void kernel_launch(void* const* d_in, const int* in_sizes, int n_in,
                              void* d_out, int out_size, void* d_ws, size_t ws_size,
                              hipStream_t stream) {
  const float* node_input = (const float*)d_in[0];
  const float* node_attr  = (const float*)d_in[1];
  const int*   edge_src   = (const int*)d_in[2];
  const int*   edge_dst   = (const int*)d_in[3];
  const float* edge_attr  = (const float*)d_in[4];
  const float* ele        = (const float*)d_in[5];
  const float* sc_w0      = (const float*)d_in[6];
  const float* sc_w1      = (const float*)d_in[7];
  const float* l1_w0      = (const float*)d_in[8];
  const float* l1_w1      = (const float*)d_in[9];
  const float* fc_w0      = (const float*)d_in[10];
  const float* fc_w1      = (const float*)d_in[11];
  const float* l2_w0      = (const float*)d_in[12];
  const float* l2_w1      = (const float*)d_in[13];
  const float* l2_w2      = (const float*)d_in[14];
  float* out = (float*)d_out;

  char* base = (char*)d_ws;
  float* y              = (float*)(base);                       // 7.68 MB (stride 192)
  unsigned short* wbuf  = (unsigned short*)(base + 7680000);    // 102.4 MB packed (orig order)
  float* ed2            = (float*)(base + 110080000);           // 7.68 MB (stride 12)
  int* counts           = (int*)(base + 122880000);
  int* offs             = (int*)(base + 122920000);
  int* cur              = (int*)(base + 122960000);
  int* order            = (int*)(base + 123000000);
  int* obeg             = (int*)(base + 123040000);
  int* ocnt             = (int*)(base + 123080000);
  int* dcur             = (int*)(base + 123120000);             // 1 KB
  unsigned short* fc1p  = (unsigned short*)(base + 123121024);  // 40 KB
  float* wt             = (float*)(base + 123161984);           // 73,728 B transposed lin2/sc
  float* l1t            = (float*)(base + 123235712);           // 22,528 B lin1t + fc0t
  int* flag             = (int*)(base + 123258240);             // 4 B scan-done flag

  // EPI mode needs ws through flag end = 123,258,240 + 4
  const bool epi = ws_size >= (size_t)123258244;

  hipMemsetAsync(counts, 0, N_NODES * sizeof(int), stream);
  hipLaunchKernelGGL(k_init, dim3(176), dim3(256), 0, stream, edge_dst, counts,
                     fc_w1, fc1p,
                     l2_w0, sc_w0, l2_w1, l2_w2, sc_w1, epi ? wt : (float*)nullptr,
                     l1_w0, l1_w1, fc_w0, epi ? l1t : (float*)nullptr,
                     epi ? flag : (int*)nullptr);
  if (epi) {
    hipLaunchKernelGGL(HIP_KERNEL_NAME(k_big<true>), dim3(1 + 2500 + 625 + 625),
                       dim3(256), 0, stream, ele, fc_w0, fc1p, wbuf,
                       node_input, node_attr, l1_w0, l1_w1, l1t, l1t + 4096,
                       l1t + 5120, y, counts, offs, cur, dcur,
                       edge_dst, order, obeg, ocnt, edge_attr, edge_src, ed2, flag);
    hipLaunchKernelGGL(HIP_KERNEL_NAME(node_agg<true>), dim3(2000), dim3(320), 0, stream,
                       y, node_input, node_attr, ed2, wbuf,
                       order, obeg, ocnt, sc_w0, sc_w1, l2_w0, l2_w1, l2_w2, out, wt);
  } else {
    hipLaunchKernelGGL(HIP_KERNEL_NAME(k_big<false>), dim3(1 + 2500 + 6250), dim3(256), 0,
                       stream, ele, fc_w0, fc1p, wbuf,
                       node_input, node_attr, l1_w0, l1_w1,
                       (float*)nullptr, (float*)nullptr, (float*)nullptr, y,
                       counts, offs, cur, dcur,
                       edge_dst, order, obeg, ocnt, edge_attr, edge_src, ed2,
                       (int*)nullptr);
    hipLaunchKernelGGL(k_perm, dim3(N_EDGES / 256), dim3(256), 0, stream,
                       edge_dst, cur, counts, offs, dcur, order, obeg, ocnt,
                       edge_attr, edge_src, ed2);
    hipLaunchKernelGGL(HIP_KERNEL_NAME(node_agg<false>), dim3(2500), dim3(256), 0, stream,
                       y, node_input, node_attr, ed2, wbuf,
                       order, obeg, ocnt, sc_w0, sc_w1, l2_w0, l2_w1, l2_w2, out,
                       (float*)nullptr);
  }
}

// Round 12
// 284.012 us; speedup vs baseline: 1.4187x; 1.4187x over previous
//
#include <hip/hip_runtime.h>
#include <cstddef>
#include <cstdint>

#define N_NODES 10000
#define N_EDGES 160000

// ---- constants ----
#define RS8    0.35355339059327373f   // 1/sqrt(8)
#define RS32   0.17677669529663687f   // 1/sqrt(32)
#define RS96   0.10206207261596575f   // 1/sqrt(96)
#define RS128  0.08838834764831845f   // 1/sqrt(128)
#define RS3    0.5773502691896258f    // 1/sqrt(3)
#define SQ3_   1.7320508075688772f
#define SQ5_   2.23606797749979f
#define A_     0.18257418583505536f   // 1/sqrt(30)
#define B_     0.31622776601683794f   // 1/sqrt(10)
#define SILU_C_ 1.6765208f
#define CS_    0.3826834323650898f    // sin(pi/8)
#define CX_    0.9238795325112867f    // cos(pi/8)
#define QDEG   0.25f                  // 1/sqrt(16)

typedef __attribute__((ext_vector_type(8))) short bf16x8;
typedef __attribute__((ext_vector_type(4))) float f32x4;
typedef __attribute__((ext_vector_type(2))) float f32x2;

__device__ inline float bf2f(unsigned v) {
  union { unsigned u; float f; } c; c.u = v << 16; return c.f;
}
__device__ inline float bfhi(unsigned v) {   // float from HIGH 16 bits
  union { unsigned u; float f; } c; c.u = v & 0xffff0000u; return c.f;
}
__device__ inline unsigned short f2bf(float f) {
  union { float f; unsigned u; } c; c.f = f;
  unsigned r = c.u + 0x7fff + ((c.u >> 16) & 1);
  return (unsigned short)(r >> 16);
}
// packed f32x2 -> 2xbf16 in one instruction (RNE, same as f2bf)
__device__ inline unsigned cvtpk2bf(float a, float b) {
  unsigned r;
  asm("v_cvt_pk_bf16_f32 %0, %1, %2" : "=v"(r) : "v"(a), "v"(b));
  return r;
}

// build fc1p (fc1 64x320 f32 -> bf16 MFMA B-fragment order, PRE-SCALED by
// K=0.125 — exact in bf16)
// + (split) transpose lin2/sc weights (wt, 18432 f)
// + transpose lin1 weights + fc0 (l1t, 5632 f)
// + grid-stride histogram of edge_dst into counts (counts pre-zeroed by memset).
__global__ void k_init(const int* __restrict__ edst, int* __restrict__ counts,
                       const float* __restrict__ fc1,
                       unsigned short* __restrict__ fc1p,
                       const float* __restrict__ w0, const float* __restrict__ sc_w0,
                       const float* __restrict__ w1, const float* __restrict__ w2,
                       const float* __restrict__ sc_w1, float* __restrict__ wt,
                       const float* __restrict__ l1_w0, const float* __restrict__ l1_w1,
                       const float* __restrict__ fc0, float* __restrict__ l1t) {
  int i = blockIdx.x * blockDim.x + threadIdx.x;
  int stride = gridDim.x * blockDim.x;
  if (i < 20480) {
    int j = i & 7, q = (i >> 3) & 3, n = (i >> 5) & 15, kq = (i >> 9) & 1, t = i >> 10;
    int k = kq * 32 + q * 8 + j;
    fc1p[i] = f2bf(fc1[k * 320 + t * 16 + n] * 0.125f);
  }
  if (wt && i >= 20480 && i < 38912) {
    int j = i - 20480;
    float* w0t  = wt;
    float* sw0t = wt + 6144;
    float* w1t  = wt + 10240;
    float* w2t  = wt + 14336;
    float* sw1t = wt + 17408;
    if (j < 6144) {
      int u = j >> 6, oc = j & 63; w0t[oc * 96 + u] = w0[u * 64 + oc];
    } else if (j < 10240) {
      int q = j - 6144; int u = q >> 6, oc = q & 63; sw0t[oc * 64 + u] = sc_w0[u * 64 + oc];
    } else if (j < 14336) {
      int q = j - 10240; int u = q >> 5, v = q & 31; w1t[v * 128 + u] = w1[u * 32 + v];
    } else if (j < 17408) {
      int q = j - 14336; int u = q >> 5, v = q & 31; w2t[v * 96 + u] = w2[u * 32 + v];
    } else {
      int q = j - 17408; int u = q >> 5, v = q & 31; sw1t[v * 32 + u] = sc_w1[u * 32 + v];
    }
  }
  if (l1t && i >= 38912 && i < 44544) {
    int j = i - 38912;
    if (j < 4096) {
      int c = j >> 6, u = j & 63;
      l1t[c * 64 + u] = l1_w0[u * 64 + c];
    } else if (j < 5120) {
      int q = j - 4096; int v = q >> 5, u = q & 31;
      l1t[4096 + v * 32 + u] = l1_w1[u * 32 + v];
    } else {
      int q = j - 5120; int k = q >> 3, m = q & 7;
      l1t[5120 + k * 8 + m] = fc0[m * 64 + k];
    }
  }
  for (int e = i; e < N_EDGES; e += stride) atomicAdd(&counts[edst[e]], 1);
}

// scan body (runs as block 0 of k_big, hidden under w_gemm blocks):
// exclusive scan of counts -> offs/cur; degree histogram + descending-degree
// exclusive scan -> dcur.
__device__ void scan_body(char* raw, const int* __restrict__ counts,
                          int* __restrict__ offs, int* __restrict__ cur,
                          int* __restrict__ dcur) {
  int* ps = (int*)raw;
  int* dbin = ps + 256;
  int t = threadIdx.x;
  dbin[t] = 0;
  int base = t * 40;
  int sum = 0;
  for (int i = 0; i < 40; ++i) {
    int idx = base + i;
    if (idx < N_NODES) sum += counts[idx];
  }
  ps[t] = sum;
  __syncthreads();
  for (int off = 1; off < 256; off <<= 1) {
    int v = (t >= off) ? ps[t - off] : 0;
    __syncthreads();
    ps[t] += v;
    __syncthreads();
  }
  int run = (t == 0) ? 0 : ps[t - 1];
  for (int i = 0; i < 40; ++i) {
    int idx = base + i;
    if (idx < N_NODES) {
      int c = counts[idx];
      offs[idx] = run; cur[idx] = run;
      run += c;
      atomicAdd(&dbin[c < 255 ? c : 255], 1);
    }
  }
  __syncthreads();
  int rb = 255 - t;
  int v = dbin[rb];
  __syncthreads();
  ps[t] = v;
  __syncthreads();
  for (int off = 1; off < 256; off <<= 1) {
    int u = (t >= off) ? ps[t - off] : 0;
    __syncthreads();
    ps[t] += u;
    __syncthreads();
  }
  dcur[rb] = ps[t] - v;
}

// Permute kernel (SLIM): per edge compute sorted position p and scatter-write
// the permuted stream ed2 (stride 12 f = 48 B): [0..8]=SH, [9]=src,
// [10]=orig edge idx, [11]=pad. eattr staged coalesced in LDS. Also the
// node scatter (descending-degree rank -> order/obeg/ocnt).
__global__ __launch_bounds__(256) void k_perm(
    const int* __restrict__ edst, int* __restrict__ cur,
    const int* __restrict__ counts, const int* __restrict__ offs,
    int* __restrict__ dcur, int* __restrict__ order,
    int* __restrict__ obeg, int* __restrict__ ocnt,
    const float* __restrict__ eattr,
    const int* __restrict__ esrc, float* __restrict__ ed2) {
  __shared__ __align__(16) float sh_ea[256 * 9];
  int t = threadIdx.x;
  int eb = blockIdx.x * 256;
  int e = eb + t;
  for (int i = t; i < 2304; i += 256) sh_ea[i] = eattr[(size_t)eb * 9 + i];
  __syncthreads();
  int d = edst[e];
  int p = atomicAdd(&cur[d], 1);
  const float* ea = sh_ea + t * 9;
  float4 r0 = {ea[0], ea[1], ea[2], ea[3]};
  float4 r1 = {ea[4], ea[5], ea[6], ea[7]};
  float4 r2 = {ea[8], __int_as_float(esrc[e]), __int_as_float(e), 0.f};
  float4* dst = (float4*)(ed2 + (size_t)p * 12);
  dst[0] = r0; dst[1] = r1; dst[2] = r2;
  if (e < N_NODES) {
    int c = counts[e];
    int b = c < 255 ? c : 255;
    int q = atomicAdd(&dcur[b], 1);
    order[q] = e; obeg[q] = offs[e]; ocnt[q] = c;
  }
}

__device__ inline f32x4 wtile(const unsigned short* __restrict__ fc1p,
                              bf16x8 a0, bf16x8 a1, int mrow, int quad, int t) {
  f32x4 acc = {0.f, 0.f, 0.f, 0.f};
  bf16x8 b0 = *(const bf16x8*)(fc1p + ((size_t)((t * 2 + 0) * 16 + mrow) * 4 + quad) * 8);
  bf16x8 b1 = *(const bf16x8*)(fc1p + ((size_t)((t * 2 + 1) * 16 + mrow) * 4 + quad) * 8);
  acc = __builtin_amdgcn_mfma_f32_16x16x32_bf16(b0, a0, acc, 0, 0, 0);
  acc = __builtin_amdgcn_mfma_f32_16x16x32_bf16(b1, a1, acc, 0, 0, 0);
  return acc;
}

struct WgemmShared {
  __align__(16) float ele[64][8];
  __align__(16) unsigned short h[64 * 72];   // 72-stride pad
};

// STREAMING MFMA radial GEMM: 64 edges/block in ORIGINAL edge order,
// writes packed wbuf (640 B/edge). fc1p pre-scaled by K; pack via
// v_cvt_pk_bf16_f32. PK=true: h-stage uses fc0t rows (v_pk_fma).
template <bool PK>
__device__ void w_gemm_body(WgemmShared& sh, int blk,
    const float* __restrict__ eleg, const float* __restrict__ fc0,
    const float* __restrict__ fc0t,
    const unsigned short* __restrict__ fc1p, unsigned short* __restrict__ wout) {
  int t = threadIdx.x;
  int eb = blk * 64;
  if (t < 128) {
    int e = t >> 1, hh = t & 1;
    ((float4*)&sh.ele[e][0])[hh] =
        *(const float4*)(eleg + (size_t)(eb + e) * 8 + hh * 4);
  }
  __syncthreads();
  #pragma unroll
  for (int ii = 0; ii < 16; ++ii) {
    int idx = t + ii * 256;
    int e = idx >> 6, k = idx & 63;
    float acc;
    if constexpr (PK) {
      f32x2 a2 = {0.f, 0.f};
      const f32x2* er = (const f32x2*)&sh.ele[e][0];
      const f32x2* fr = (const f32x2*)(fc0t + k * 8);
      #pragma unroll
      for (int m = 0; m < 4; ++m) a2 += er[m] * fr[m];
      acc = a2.x + a2.y;
    } else {
      acc = 0.f;
      #pragma unroll
      for (int m = 0; m < 8; ++m) acc += sh.ele[e][m] * fc0[m * 64 + k];
    }
    acc *= RS8;
    float hv = SILU_C_ * acc / (1.f + __expf(-acc));
    sh.h[e * 72 + k] = f2bf(hv);
  }
  __syncthreads();

  int wv = t >> 6, lane = t & 63;
  int m0 = wv * 16;
  int mrow = lane & 15, quad = lane >> 4;
  bf16x8 a0 = *(const bf16x8*)(sh.h + (m0 + mrow) * 72 + quad * 8);
  bf16x8 a1 = *(const bf16x8*)(sh.h + (m0 + mrow) * 72 + 32 + quad * 8);
  char* wbase = (char*)wout + (size_t)(eb + m0 + mrow) * 640;
  #pragma unroll
  for (int tt = 0; tt < 4; ++tt) {
    f32x4 Av = wtile(fc1p, a0, a1, mrow, quad, tt);
    f32x4 Bv = wtile(fc1p, a0, a1, mrow, quad, tt + 4);
    uint4 st;
    st.x = cvtpk2bf(Av[0], Bv[0]);
    st.y = cvtpk2bf(Av[1], Bv[1]);
    st.z = cvtpk2bf(Av[2], Bv[2]);
    st.w = cvtpk2bf(Av[3], Bv[3]);
    *(uint4*)(wbase + 64 * tt + 16 * quad) = st;
  }
  #pragma unroll
  for (int tt = 8; tt < 12; ++tt) {
    f32x4 Cv = wtile(fc1p, a0, a1, mrow, quad, tt);
    uint2 st;
    st.x = cvtpk2bf(Cv[0], Cv[1]);
    st.y = cvtpk2bf(Cv[2], Cv[3]);
    *(uint2*)(wbase + 256 + 32 * (tt - 8) + 8 * quad) = st;
  }
  #pragma unroll
  for (int tt = 12; tt < 14; ++tt) {
    f32x4 Dv = wtile(fc1p, a0, a1, mrow, quad, tt);
    f32x4 Ev = wtile(fc1p, a0, a1, mrow, quad, tt + 2);
    f32x4 Fv = wtile(fc1p, a0, a1, mrow, quad, tt + 4);
    f32x4 Gv = wtile(fc1p, a0, a1, mrow, quad, tt + 6);
    char* db = wbase + 384 + 128 * (tt - 12) + 32 * quad;
    uint4 s0, s1;
    s0.x = cvtpk2bf(Dv[0], Ev[0]); s0.y = cvtpk2bf(Fv[0], Gv[0]);
    s0.z = cvtpk2bf(Dv[1], Ev[1]); s0.w = cvtpk2bf(Fv[1], Gv[1]);
    s1.x = cvtpk2bf(Dv[2], Ev[2]); s1.y = cvtpk2bf(Fv[2], Gv[2]);
    s1.z = cvtpk2bf(Dv[3], Ev[3]); s1.w = cvtpk2bf(Fv[3], Gv[3]);
    *(uint4*)(db) = s0;
    *(uint4*)(db + 16) = s1;
  }
}

// node_pre (split mode): k_out-style batched lin1, pk-packed dots.
#define NBK_PRE 16
__device__ void node_pre_body2(float* sh, int blk,
    const float* __restrict__ xin, const float* __restrict__ attr,
    const float* __restrict__ l1w0t, const float* __restrict__ l1w1t,
    float* __restrict__ y) {
  int t = threadIdx.x;
  int n0 = blk * NBK_PRE;
  for (int i = t; i < NBK_PRE * 160; i += 256) {
    int n = i / 160, c = i - n * 160;
    float v = xin[(size_t)(n0 + n) * 160 + c];
    int dst;
    if (c < 64) dst = c;
    else { int q = c - 64; int u = q / 3; int ii = q - u * 3; dst = 64 + ii * 32 + u; }
    sh[n * 176 + dst] = v;
  }
  if (t < NBK_PRE) sh[2816 + t] = attr[n0 + t];
  __syncthreads();
  if (t < 64) {
    const float4* wr = (const float4*)(l1w0t + t * 64);
    f32x2 a2[NBK_PRE];
    #pragma unroll
    for (int n = 0; n < NBK_PRE; ++n) a2[n] = (f32x2){0.f, 0.f};
    #pragma unroll 4
    for (int c4 = 0; c4 < 16; ++c4) {
      float4 wv = wr[c4];
      f32x2 wlo = {wv.x, wv.y}, whi = {wv.z, wv.w};
      #pragma unroll
      for (int n = 0; n < NBK_PRE; ++n) {
        float4 xv = *(const float4*)(sh + n * 176 + 4 * c4);
        f32x2 xlo = {xv.x, xv.y}, xhi = {xv.z, xv.w};
        a2[n] += xlo * wlo;
        a2[n] += xhi * whi;
      }
    }
    #pragma unroll
    for (int n = 0; n < NBK_PRE; ++n)
      y[(size_t)(n0 + n) * 192 + t] = (a2[n].x + a2[n].y) * sh[2816 + n] * 0.125f;
  } else if (t < 160) {
    int q = t - 64, v = q / 3, ii = q - v * 3;
    const float4* wr = (const float4*)(l1w1t + v * 32);
    f32x2 a2[NBK_PRE];
    #pragma unroll
    for (int n = 0; n < NBK_PRE; ++n) a2[n] = (f32x2){0.f, 0.f};
    #pragma unroll 2
    for (int c4 = 0; c4 < 8; ++c4) {
      float4 wv = wr[c4];
      f32x2 wlo = {wv.x, wv.y}, whi = {wv.z, wv.w};
      #pragma unroll
      for (int n = 0; n < NBK_PRE; ++n) {
        float4 xv = *(const float4*)(sh + n * 176 + 64 + ii * 32 + 4 * c4);
        f32x2 xlo = {xv.x, xv.y}, xhi = {xv.z, xv.w};
        a2[n] += xlo * wlo;
        a2[n] += xhi * whi;
      }
    }
    #pragma unroll
    for (int n = 0; n < NBK_PRE; ++n) {
      float r = (a2[n].x + a2[n].y) * sh[2816 + n] * RS32;
      float* yr = y + (size_t)(n0 + n) * 192 + 64 + v * 4;
      yr[ii] = r;
      if (ii == 2) yr[3] = 0.f;
    }
  }
}

// OLD node_pre (fallback only)
__device__ void node_pre_body(int blk,
    const float* __restrict__ xin, const float* __restrict__ attr,
    const float* __restrict__ l1_w0, const float* __restrict__ l1_w1,
    float* __restrict__ y) {
  int idx = blk * 256 + threadIdx.x;
  int n = idx / 160, c = idx - n * 160;
  const float* xr = xin + (size_t)n * 160;
  float a = attr[n];
  if (c < 64) {
    float y_ = 0.f;
    #pragma unroll 8
    for (int u = 0; u < 64; ++u) y_ += xr[u] * l1_w0[u * 64 + c];
    y[(size_t)n * 192 + c] = y_ * a * 0.125f;
  } else {
    int t = c - 64; int v = t / 3, i = t - v * 3;
    float y_ = 0.f;
    #pragma unroll 8
    for (int u = 0; u < 32; ++u) y_ += xr[64 + u * 3 + i] * l1_w1[u * 32 + v];
    y[(size_t)n * 192 + 64 + v * 4 + i] = y_ * a * RS32;
    if (i == 2) y[(size_t)n * 192 + 64 + v * 4 + 3] = 0.f;
  }
}

// big fused mid-stage (launched right after k_init; no perm dependency):
// block 0            = scan (hidden under w_gemm)
// blocks [1,2501)    = w_gemm (original edge order)
// PRE2=true : [2501,3126) = node_pre_body2
// PRE2=false: [2501,8751) = old node_pre
template <bool PRE2>
__global__ __launch_bounds__(256) void k_big(
    const float* __restrict__ eleg, const float* __restrict__ fc0,
    const unsigned short* __restrict__ fc1p, unsigned short* __restrict__ wout,
    const float* __restrict__ xin, const float* __restrict__ attr,
    const float* __restrict__ l1_w0, const float* __restrict__ l1_w1,
    const float* __restrict__ l1w0t, const float* __restrict__ l1w1t,
    const float* __restrict__ fc0t, float* __restrict__ y,
    const int* __restrict__ counts, int* __restrict__ offs,
    int* __restrict__ cur, int* __restrict__ dcur) {
  __shared__ __align__(16) char shraw[11328];
  if (blockIdx.x == 0) {
    scan_body(shraw, counts, offs, cur, dcur);
  } else if (blockIdx.x <= 2500) {
    w_gemm_body<PRE2>(*(WgemmShared*)shraw, blockIdx.x - 1, eleg, fc0, fc0t, fc1p, wout);
  } else if (PRE2) {
    node_pre_body2((float*)shraw, blockIdx.x - 2501, xin, attr, l1w0t, l1w1t, y);
  } else {
    node_pre_body(blockIdx.x - 2501, xin, attr, l1_w0, l1_w1, y);
  }
}

// node_agg:
// EPI=true : 2000 blocks x 5 waves (320 thr), ONE NODE PER WAVE in
//            degree-desc order (rank = blk*5+wid). R9 scalarized loop
//            (ed2 s_load, SALU bases). Bank-padded component-major LDS
//            (node stride 1152, 5 nodes = 23.1 KB); SINGLE-PASS epilogue:
//            thread t owns channel t (320==320), weight float4 reused
//            over 5 nodes, pk-packed dots.
// EPI=false: 2500x4x256 fallback with original fused epilogue.
#define WREG 960
template <bool EPI>
__global__ __launch_bounds__(320) void node_agg(
    const float* __restrict__ y, const float* __restrict__ xin,
    const float* __restrict__ attr, const float* __restrict__ ed2,
    const unsigned short* __restrict__ wbuf,
    const int* __restrict__ order, const int* __restrict__ obeg,
    const int* __restrict__ ocnt,
    const float* __restrict__ sc_w0, const float* __restrict__ sc_w1,
    const float* __restrict__ w0, const float* __restrict__ w1,
    const float* __restrict__ w2, float* __restrict__ out,
    const float* __restrict__ wt) {
  int tid = threadIdx.x, wid = tid >> 6, lane = tid & 63, l31 = lane & 31;
  int gw = blockIdx.x * (EPI ? 5 : 4) + wid;
  // fixed per-lane byte offsets (loop-invariant)
  int voY  = 4 * lane;           // y scalar block
  int voX  = 256 + 16 * l31;     // y vector float4 {x0,x1,x2,0}
  int voAB = 4 * lane;           // wbuf AB
  int voC  = 256 + 2 * lane;     // wbuf C
  int voDG = 384 + 8 * l31;      // wbuf DEFG

#define E_LOAD(S, idx)                                                         \
  if ((idx) < cnt) {                                                           \
    int ro_ = __builtin_amdgcn_readfirstlane(beg + (idx));                     \
    const float4* ep = (const float4*)(ed2 + (size_t)ro_ * 12);                \
    PE0##S = ep[0]; PE1##S = ep[1]; PE2##S = ep[2];                            \
  }
#define V_LOAD(S, idx)                                                         \
  if ((idx) < cnt) {                                                           \
    int srcn = __builtin_amdgcn_readfirstlane(__float_as_int(PE2##S.y));       \
    int eorg = __builtin_amdgcn_readfirstlane(__float_as_int(PE2##S.z));       \
    const char* yb = (const char*)y + (size_t)srcn * 768;                      \
    Y##S = *(const float*)(yb + voY);                                          \
    X##S = *(const f32x4*)(yb + voX);                                          \
    const char* wb = (const char*)wbuf + (size_t)eorg * 640;                   \
    AB##S = *(const unsigned*)(wb + voAB);                                     \
    Cw##S = *(const unsigned short*)(wb + voC);                                \
    DG##S = *(const uint2*)(wb + voDG);                                        \
  }
#define COMPUTE(S)                                                             \
  {                                                                            \
    float e0 = PE0##S.x, ey = PE0##S.y, ez = PE0##S.z, ex = PE0##S.w;          \
    float q0 = PE1##S.x, q1 = PE1##S.y, q2 = PE1##S.z, q3 = PE1##S.w;          \
    float q4 = PE2##S.x;                                                       \
    float Yv = Y##S, x0 = X##S.x, x1 = X##S.y, x2 = X##S.z;                    \
    float vA = bf2f(AB##S), vB = bfhi(AB##S), vC = bf2f(Cw##S);                \
    float vD = bf2f(DG##S.x), vE = bfhi(DG##S.x);                              \
    float vF = bf2f(DG##S.y), vG = bfhi(DG##S.y);                              \
    aK0 += Yv * e0 * vA;                                                       \
    float tB = Yv * vB; aK2x += tB * ey; aK2y += tB * ez; aK2z += tB * ex;     \
    float tC = Yv * vC;                                                        \
    aK5a += tC * q0; aK5b += tC * q1; aK5c += tC * q2;                         \
    aK5d += tC * q3; aK5e += tC * q4;                                          \
    float t1 = x0 * ey + x1 * ez + x2 * ex; aK1 += (RS3 * vE) * t1;            \
    float s3 = e0 * vD; aK3x += x0 * s3; aK3y += x1 * s3; aK3z += x2 * s3;     \
    float s4 = SQ3_ * vG;                                                      \
    aK4x += s4 * (B_ * (x2 * q0 + x1 * q1 - x0 * q4) - A_ * x0 * q2);          \
    aK4y += s4 * (B_ * (x0 * q1 + x2 * q3) + 2.f * A_ * x1 * q2);              \
    aK4z += s4 * (B_ * (x0 * q0 + x1 * q3 + x2 * q4) - A_ * x2 * q2);          \
    float s6 = SQ5_ * vF;                                                      \
    aK6a += s6 * (-B_ * (x0 * ex + x2 * ey));                                  \
    aK6b += s6 * (-B_ * (x0 * ez + x1 * ey));                                  \
    aK6c += s6 * ( A_ * (x0 * ey + x2 * ex - 2.f * x1 * ez));                  \
    aK6d += s6 * (-B_ * (x1 * ex + x2 * ez));                                  \
    aK6e += s6 * ( B_ * (x0 * ey - x2 * ex));                                  \
  }
#define LWAIT __asm__ volatile("s_waitcnt lgkmcnt(0)" ::: "memory")

  int n = order[gw], beg = obeg[gw], cnt = ocnt[gw];

  float aK0 = 0.f, aK2x = 0.f, aK2y = 0.f, aK2z = 0.f;
  float aK5a = 0.f, aK5b = 0.f, aK5c = 0.f, aK5d = 0.f, aK5e = 0.f;
  float aK1 = 0.f, aK3x = 0.f, aK3y = 0.f, aK3z = 0.f;
  float aK4x = 0.f, aK4y = 0.f, aK4z = 0.f;
  float aK6a = 0.f, aK6b = 0.f, aK6c = 0.f, aK6d = 0.f, aK6e = 0.f;

  float4 PE0a, PE1a, PE2a, PE0b, PE1b, PE2b;
  float Ya, Yb; f32x4 Xa, Xb;
  unsigned ABa, ABb; unsigned short Cwa, Cwb;
  uint2 DGa, DGb;

  E_LOAD(a, 0)
  E_LOAD(b, 1)
  V_LOAD(a, 0)

  int i = 0;
  while (i < cnt) {
    V_LOAD(b, i + 1)
    COMPUTE(a)
    E_LOAD(a, i + 2)
    ++i; if (i >= cnt) break;
    V_LOAD(a, i + 1)
    COMPUTE(b)
    E_LOAD(b, i + 2)
    ++i;
  }

  if constexpr (EPI) {
    // per-node layout (floats, node stride 1152):
    //   R[0,984)  bank-padded: m0@0 (96), m1@96 stride 132, m2@488 stride 100
    //   xin[984,1144), pad[1144,1152)
    // meta: attr @5760+wid, nid @int 5768+wid
    __shared__ __align__(16) float sepi[5 * 1152 + 16];
    float* R = sepi + wid * 1152;
    R[lane]        = aK0  * QDEG;   // m0 u=lane          (k0)
    R[96 + lane]   = aK2x * QDEG;   // m1 ii=0 u=lane     (k2)
    R[228 + lane]  = aK2y * QDEG;   // m1 ii=1
    R[360 + lane]  = aK2z * QDEG;   // m1 ii=2
    R[488 + lane]  = aK5a * QDEG;   // m2 kk=0 u=lane     (k5)
    R[588 + lane]  = aK5b * QDEG;
    R[688 + lane]  = aK5c * QDEG;
    R[788 + lane]  = aK5d * QDEG;
    R[888 + lane]  = aK5e * QDEG;
    if (lane < 32) {
      R[64 + lane]   = aK1  * QDEG; // m0 u=64+lane       (k1)
      R[160 + lane]  = aK3x * QDEG; // m1 ii=0 u=64+lane  (k3)
      R[292 + lane]  = aK3y * QDEG;
      R[424 + lane]  = aK3z * QDEG;
      R[192 + lane]  = aK4x * QDEG; // m1 ii=0 u=96+lane  (k4)
      R[324 + lane]  = aK4y * QDEG;
      R[456 + lane]  = aK4z * QDEG;
      R[552 + lane]  = aK6a * QDEG; // m2 kk=0 u=64+lane  (k6)
      R[652 + lane]  = aK6b * QDEG;
      R[752 + lane]  = aK6c * QDEG;
      R[852 + lane]  = aK6d * QDEG;
      R[952 + lane]  = aK6e * QDEG;
    }
    if (lane < 40)
      *(float4*)(sepi + wid * 1152 + 984 + 4 * lane) =
          *(const float4*)(xin + (size_t)n * 160 + 4 * lane);
    if (lane == 40) sepi[5760 + wid] = attr[n];
    if (lane == 41) ((int*)sepi)[5768 + wid] = n;
    __syncthreads();
    const float* w0t  = wt;
    const float* sw0t = wt + 6144;
    const float* w1t  = wt + 10240;
    const float* w2t  = wt + 14336;
    const float* sw1t = wt + 17408;
    int ch = tid;  // 320 threads == 320 channels, single pass
    f32x2 a2[5];
    float accs[5] = {0.f, 0.f, 0.f, 0.f, 0.f};
    f32x2 s2[5];
    #pragma unroll
    for (int k = 0; k < 5; ++k) { a2[k] = (f32x2){0.f, 0.f}; s2[k] = (f32x2){0.f, 0.f}; }
    if (ch < 64) {
      const float4* wr  = (const float4*)(w0t + ch * 96);
      const float4* swr = (const float4*)(sw0t + ch * 64);
      #pragma unroll 4
      for (int c = 0; c < 24; ++c) {
        float4 wv = wr[c];
        f32x2 wlo = {wv.x, wv.y}, whi = {wv.z, wv.w};
        #pragma unroll
        for (int k = 0; k < 5; ++k) {
          float4 rv = *(const float4*)(sepi + k * 1152 + 4 * c);
          f32x2 rlo = {rv.x, rv.y}, rhi = {rv.z, rv.w};
          a2[k] += rlo * wlo;
          a2[k] += rhi * whi;
        }
      }
      #pragma unroll 4
      for (int c = 0; c < 16; ++c) {
        float4 wv = swr[c];
        f32x2 wlo = {wv.x, wv.y}, whi = {wv.z, wv.w};
        #pragma unroll
        for (int k = 0; k < 5; ++k) {
          float4 xv = *(const float4*)(sepi + k * 1152 + 984 + 4 * c);
          f32x2 xlo = {xv.x, xv.y}, xhi = {xv.z, xv.w};
          s2[k] += xlo * wlo;
          s2[k] += xhi * whi;
        }
      }
      #pragma unroll
      for (int k = 0; k < 5; ++k) {
        float a = sepi[5760 + k]; int nid = ((const int*)sepi)[5768 + k];
        float o = a2[k].x + a2[k].y, sv = s2[k].x + s2[k].y;
        out[(size_t)nid * 320 + ch] =
            CS_ * (sv * a * 0.125f) + CX_ * (o * a * RS96);
      }
    } else if (ch < 160) {
      int q = ch - 64, v = q / 3, ii = q - v * 3;
      const float4* wr = (const float4*)(w1t + v * 128);
      #pragma unroll 4
      for (int c = 0; c < 32; ++c) {
        float4 wv = wr[c];
        f32x2 wlo = {wv.x, wv.y}, whi = {wv.z, wv.w};
        #pragma unroll
        for (int k = 0; k < 5; ++k) {
          float4 rv = *(const float4*)(sepi + k * 1152 + 96 + ii * 132 + 4 * c);
          f32x2 rlo = {rv.x, rv.y}, rhi = {rv.z, rv.w};
          a2[k] += rlo * wlo;
          a2[k] += rhi * whi;
        }
      }
      for (int u = 0; u < 32; ++u) {
        float wv = sw1t[v * 32 + u];
        #pragma unroll
        for (int k = 0; k < 5; ++k)
          accs[k] += sepi[k * 1152 + 984 + 64 + 3 * u + ii] * wv;
      }
      #pragma unroll
      for (int k = 0; k < 5; ++k) {
        float a = sepi[5760 + k]; int nid = ((const int*)sepi)[5768 + k];
        float o = a2[k].x + a2[k].y;
        out[(size_t)nid * 320 + ch] =
            CS_ * (accs[k] * a * RS32) + CX_ * (o * a * RS128);
      }
    } else {
      int q = ch - 160, v = q / 5, kk = q - v * 5;
      const float4* wr = (const float4*)(w2t + v * 96);
      #pragma unroll 4
      for (int c = 0; c < 24; ++c) {
        float4 wv = wr[c];
        f32x2 wlo = {wv.x, wv.y}, whi = {wv.z, wv.w};
        #pragma unroll
        for (int k = 0; k < 5; ++k) {
          float4 rv = *(const float4*)(sepi + k * 1152 + 488 + kk * 100 + 4 * c);
          f32x2 rlo = {rv.x, rv.y}, rhi = {rv.z, rv.w};
          a2[k] += rlo * wlo;
          a2[k] += rhi * whi;
        }
      }
      #pragma unroll
      for (int k = 0; k < 5; ++k) {
        float a = sepi[5760 + k]; int nid = ((const int*)sepi)[5768 + k];
        float o = a2[k].x + a2[k].y;
        out[(size_t)nid * 320 + ch] = o * a * RS96;
      }
    }
  } else {
    // fallback: original fused epilogue (256-thread launch)
    __shared__ __align__(16) float smem[4 * WREG];
    float* R = smem + wid * WREG;
    R[lane]            = aK0  * QDEG;
    R[96 + 3 * lane]   = aK2x * QDEG;
    R[97 + 3 * lane]   = aK2y * QDEG;
    R[98 + 3 * lane]   = aK2z * QDEG;
    R[480 + 5 * lane]  = aK5a * QDEG;
    R[481 + 5 * lane]  = aK5b * QDEG;
    R[482 + 5 * lane]  = aK5c * QDEG;
    R[483 + 5 * lane]  = aK5d * QDEG;
    R[484 + 5 * lane]  = aK5e * QDEG;
    if (lane < 32) {
      R[64 + lane]       = aK1  * QDEG;
      R[288 + 3 * lane]  = aK3x * QDEG;
      R[289 + 3 * lane]  = aK3y * QDEG;
      R[290 + 3 * lane]  = aK3z * QDEG;
      R[384 + 3 * lane]  = aK4x * QDEG;
      R[385 + 3 * lane]  = aK4y * QDEG;
      R[386 + 3 * lane]  = aK4z * QDEG;
      R[800 + 5 * lane]  = aK6a * QDEG;
      R[801 + 5 * lane]  = aK6b * QDEG;
      R[802 + 5 * lane]  = aK6c * QDEG;
      R[803 + 5 * lane]  = aK6d * QDEG;
      R[804 + 5 * lane]  = aK6e * QDEG;
    }
    LWAIT;
    float a = attr[n];
    const float* xr = xin + (size_t)n * 160;
    float* orow = out + (size_t)n * 320;
    #pragma unroll
    for (int jo = 0; jo < 5; ++jo) {
      int oc = lane + 64 * jo;
      float res;
      if (oc < 64) {
        float o = 0.f, sv = 0.f;
        #pragma unroll 8
        for (int u = 0; u < 96; ++u) o += R[u] * w0[u * 64 + oc];
        #pragma unroll 8
        for (int u = 0; u < 64; ++u) sv += xr[u] * sc_w0[u * 64 + oc];
        res = CS_ * (sv * a * 0.125f) + CX_ * (o * a * RS96);
      } else if (oc < 160) {
        int t2 = oc - 64, v = t2 / 3, ii = t2 - v * 3;
        float o = 0.f, sv = 0.f;
        #pragma unroll 8
        for (int u = 0; u < 128; ++u) o += R[96 + u * 3 + ii] * w1[u * 32 + v];
        #pragma unroll 8
        for (int u = 0; u < 32; ++u) sv += xr[64 + u * 3 + ii] * sc_w1[u * 32 + v];
        res = CS_ * (sv * a * RS32) + CX_ * (o * a * RS128);
      } else {
        int t2 = oc - 160, v = t2 / 5, kk = t2 - v * 5;
        float o = 0.f;
        #pragma unroll 8
        for (int u = 0; u < 96; ++u) o += R[480 + u * 5 + kk] * w2[u * 32 + v];
        res = o * a * RS96;
      }
      orow[oc] = res;
    }
  }
#undef E_LOAD
#undef V_LOAD
#undef COMPUTE
#undef LWAIT
}

extern "C" void kernel_launch(void* const* d_in, const int* in_sizes, int n_in,
                              void* d_out, int out_size, void* d_ws, size_t ws_size,
                              hipStream_t stream) {
  const float* node_input = (const float*)d_in[0];
  const float* node_attr  = (const float*)d_in[1];
  const int*   edge_src   = (const int*)d_in[2];
  const int*   edge_dst   = (const int*)d_in[3];
  const float* edge_attr  = (const float*)d_in[4];
  const float* ele        = (const float*)d_in[5];
  const float* sc_w0      = (const float*)d_in[6];
  const float* sc_w1      = (const float*)d_in[7];
  const float* l1_w0      = (const float*)d_in[8];
  const float* l1_w1      = (const float*)d_in[9];
  const float* fc_w0      = (const float*)d_in[10];
  const float* fc_w1      = (const float*)d_in[11];
  const float* l2_w0      = (const float*)d_in[12];
  const float* l2_w1      = (const float*)d_in[13];
  const float* l2_w2      = (const float*)d_in[14];
  float* out = (float*)d_out;

  char* base = (char*)d_ws;
  float* y              = (float*)(base);                       // 7.68 MB (stride 192)
  unsigned short* wbuf  = (unsigned short*)(base + 7680000);    // 102.4 MB packed (orig order)
  float* ed2            = (float*)(base + 110080000);           // 7.68 MB (stride 12)
  int* counts           = (int*)(base + 122880000);
  int* offs             = (int*)(base + 122920000);
  int* cur              = (int*)(base + 122960000);
  int* order            = (int*)(base + 123000000);
  int* obeg             = (int*)(base + 123040000);
  int* ocnt             = (int*)(base + 123080000);
  int* dcur             = (int*)(base + 123120000);             // 1 KB
  unsigned short* fc1p  = (unsigned short*)(base + 123121024);  // 40 KB
  float* wt             = (float*)(base + 123161984);           // 73,728 B transposed lin2/sc
  float* l1t            = (float*)(base + 123235712);           // 22,528 B lin1t + fc0t

  // EPI mode needs ws through l1t end = 123,235,712 + 22,528
  const bool epi = ws_size >= (size_t)123258240;

  hipMemsetAsync(counts, 0, N_NODES * sizeof(int), stream);
  hipLaunchKernelGGL(k_init, dim3(176), dim3(256), 0, stream, edge_dst, counts,
                     fc_w1, fc1p,
                     l2_w0, sc_w0, l2_w1, l2_w2, sc_w1, epi ? wt : (float*)nullptr,
                     l1_w0, l1_w1, fc_w0, epi ? l1t : (float*)nullptr);
  if (epi) {
    hipLaunchKernelGGL(HIP_KERNEL_NAME(k_big<true>), dim3(1 + 2500 + 625), dim3(256), 0,
                       stream, ele, fc_w0, fc1p, wbuf,
                       node_input, node_attr, l1_w0, l1_w1, l1t, l1t + 4096,
                       l1t + 5120, y, counts, offs, cur, dcur);
    hipLaunchKernelGGL(k_perm, dim3(N_EDGES / 256), dim3(256), 0, stream,
                       edge_dst, cur, counts, offs, dcur, order, obeg, ocnt,
                       edge_attr, edge_src, ed2);
    hipLaunchKernelGGL(HIP_KERNEL_NAME(node_agg<true>), dim3(2000), dim3(320), 0, stream,
                       y, node_input, node_attr, ed2, wbuf,
                       order, obeg, ocnt, sc_w0, sc_w1, l2_w0, l2_w1, l2_w2, out, wt);
  } else {
    hipLaunchKernelGGL(HIP_KERNEL_NAME(k_big<false>), dim3(1 + 2500 + 6250), dim3(256), 0,
                       stream, ele, fc_w0, fc1p, wbuf,
                       node_input, node_attr, l1_w0, l1_w1,
                       (float*)nullptr, (float*)nullptr, (float*)nullptr, y,
                       counts, offs, cur, dcur);
    hipLaunchKernelGGL(k_perm, dim3(N_EDGES / 256), dim3(256), 0, stream,
                       edge_dst, cur, counts, offs, dcur, order, obeg, ocnt,
                       edge_attr, edge_src, ed2);
    hipLaunchKernelGGL(HIP_KERNEL_NAME(node_agg<false>), dim3(2500), dim3(256), 0, stream,
                       y, node_input, node_attr, ed2, wbuf,
                       order, obeg, ocnt, sc_w0, sc_w1, l2_w0, l2_w1, l2_w2, out,
                       (float*)nullptr);
  }
}

// Round 13
// 255.361 us; speedup vs baseline: 1.5779x; 1.1122x over previous
//
#include <hip/hip_runtime.h>
#include <cstddef>
#include <cstdint>

#define N_NODES 10000
#define N_EDGES 160000

// ---- constants ----
#define RS8    0.35355339059327373f   // 1/sqrt(8)
#define RS32   0.17677669529663687f   // 1/sqrt(32)
#define RS96   0.10206207261596575f   // 1/sqrt(96)
#define RS128  0.08838834764831845f   // 1/sqrt(128)
#define RS3    0.5773502691896258f    // 1/sqrt(3)
#define SQ3_   1.7320508075688772f
#define SQ5_   2.23606797749979f
#define A_     0.18257418583505536f   // 1/sqrt(30)
#define B_     0.31622776601683794f   // 1/sqrt(10)
#define SILU_C_ 1.6765208f
#define CS_    0.3826834323650898f    // sin(pi/8)
#define CX_    0.9238795325112867f    // cos(pi/8)
#define QDEG   0.25f                  // 1/sqrt(16)

typedef __attribute__((ext_vector_type(8))) short bf16x8;
typedef __attribute__((ext_vector_type(4))) float f32x4;
typedef __attribute__((ext_vector_type(2))) float f32x2;

__device__ inline float bf2f(unsigned v) {
  union { unsigned u; float f; } c; c.u = v << 16; return c.f;
}
__device__ inline float bfhi(unsigned v) {   // float from HIGH 16 bits
  union { unsigned u; float f; } c; c.u = v & 0xffff0000u; return c.f;
}
__device__ inline unsigned short f2bf(float f) {
  union { float f; unsigned u; } c; c.f = f;
  unsigned r = c.u + 0x7fff + ((c.u >> 16) & 1);
  return (unsigned short)(r >> 16);
}
// packed f32x2 -> 2xbf16 in one instruction (RNE, same as f2bf)
__device__ inline unsigned cvtpk2bf(float a, float b) {
  unsigned r;
  asm("v_cvt_pk_bf16_f32 %0, %1, %2" : "=v"(r) : "v"(a), "v"(b));
  return r;
}

// build fc1p (fc1 64x320 f32 -> bf16 MFMA B-fragment order, PRE-SCALED by
// K=0.125 — exact in bf16)
// + (split) transpose lin2/sc weights (wt, 18432 f)
// + transpose lin1 weights + fc0 (l1t, 5632 f)
// + grid-stride histogram of edge_dst into counts (counts pre-zeroed by memset).
__global__ void k_init(const int* __restrict__ edst, int* __restrict__ counts,
                       const float* __restrict__ fc1,
                       unsigned short* __restrict__ fc1p,
                       const float* __restrict__ w0, const float* __restrict__ sc_w0,
                       const float* __restrict__ w1, const float* __restrict__ w2,
                       const float* __restrict__ sc_w1, float* __restrict__ wt,
                       const float* __restrict__ l1_w0, const float* __restrict__ l1_w1,
                       const float* __restrict__ fc0, float* __restrict__ l1t) {
  int i = blockIdx.x * blockDim.x + threadIdx.x;
  int stride = gridDim.x * blockDim.x;
  if (i < 20480) {
    int j = i & 7, q = (i >> 3) & 3, n = (i >> 5) & 15, kq = (i >> 9) & 1, t = i >> 10;
    int k = kq * 32 + q * 8 + j;
    fc1p[i] = f2bf(fc1[k * 320 + t * 16 + n] * 0.125f);
  }
  if (wt && i >= 20480 && i < 38912) {
    int j = i - 20480;
    float* w0t  = wt;
    float* sw0t = wt + 6144;
    float* w1t  = wt + 10240;
    float* w2t  = wt + 14336;
    float* sw1t = wt + 17408;
    if (j < 6144) {
      int u = j >> 6, oc = j & 63; w0t[oc * 96 + u] = w0[u * 64 + oc];
    } else if (j < 10240) {
      int q = j - 6144; int u = q >> 6, oc = q & 63; sw0t[oc * 64 + u] = sc_w0[u * 64 + oc];
    } else if (j < 14336) {
      int q = j - 10240; int u = q >> 5, v = q & 31; w1t[v * 128 + u] = w1[u * 32 + v];
    } else if (j < 17408) {
      int q = j - 14336; int u = q >> 5, v = q & 31; w2t[v * 96 + u] = w2[u * 32 + v];
    } else {
      int q = j - 17408; int u = q >> 5, v = q & 31; sw1t[v * 32 + u] = sc_w1[u * 32 + v];
    }
  }
  if (l1t && i >= 38912 && i < 44544) {
    int j = i - 38912;
    if (j < 4096) {
      int c = j >> 6, u = j & 63;
      l1t[c * 64 + u] = l1_w0[u * 64 + c];
    } else if (j < 5120) {
      int q = j - 4096; int v = q >> 5, u = q & 31;
      l1t[4096 + v * 32 + u] = l1_w1[u * 32 + v];
    } else {
      int q = j - 5120; int k = q >> 3, m = q & 7;
      l1t[5120 + k * 8 + m] = fc0[m * 64 + k];
    }
  }
  for (int e = i; e < N_EDGES; e += stride) atomicAdd(&counts[edst[e]], 1);
}

// scan body (runs as block 0 of k_big, hidden under w_gemm blocks):
// exclusive scan of counts -> offs/cur; degree histogram + descending-degree
// exclusive scan -> dcur.
__device__ void scan_body(char* raw, const int* __restrict__ counts,
                          int* __restrict__ offs, int* __restrict__ cur,
                          int* __restrict__ dcur) {
  int* ps = (int*)raw;
  int* dbin = ps + 256;
  int t = threadIdx.x;
  dbin[t] = 0;
  int base = t * 40;
  int sum = 0;
  for (int i = 0; i < 40; ++i) {
    int idx = base + i;
    if (idx < N_NODES) sum += counts[idx];
  }
  ps[t] = sum;
  __syncthreads();
  for (int off = 1; off < 256; off <<= 1) {
    int v = (t >= off) ? ps[t - off] : 0;
    __syncthreads();
    ps[t] += v;
    __syncthreads();
  }
  int run = (t == 0) ? 0 : ps[t - 1];
  for (int i = 0; i < 40; ++i) {
    int idx = base + i;
    if (idx < N_NODES) {
      int c = counts[idx];
      offs[idx] = run; cur[idx] = run;
      run += c;
      atomicAdd(&dbin[c < 255 ? c : 255], 1);
    }
  }
  __syncthreads();
  int rb = 255 - t;
  int v = dbin[rb];
  __syncthreads();
  ps[t] = v;
  __syncthreads();
  for (int off = 1; off < 256; off <<= 1) {
    int u = (t >= off) ? ps[t - off] : 0;
    __syncthreads();
    ps[t] += u;
    __syncthreads();
  }
  dcur[rb] = ps[t] - v;
}

// Permute kernel (SLIM): per edge compute sorted position p and scatter-write
// the permuted stream ed2 (stride 12 f = 48 B): [0..8]=SH, [9]=src,
// [10]=orig edge idx, [11]=pad. eattr staged coalesced in LDS. Also the
// node scatter (descending-degree rank -> order/obeg/ocnt).
__global__ __launch_bounds__(256) void k_perm(
    const int* __restrict__ edst, int* __restrict__ cur,
    const int* __restrict__ counts, const int* __restrict__ offs,
    int* __restrict__ dcur, int* __restrict__ order,
    int* __restrict__ obeg, int* __restrict__ ocnt,
    const float* __restrict__ eattr,
    const int* __restrict__ esrc, float* __restrict__ ed2) {
  __shared__ __align__(16) float sh_ea[256 * 9];
  int t = threadIdx.x;
  int eb = blockIdx.x * 256;
  int e = eb + t;
  for (int i = t; i < 2304; i += 256) sh_ea[i] = eattr[(size_t)eb * 9 + i];
  __syncthreads();
  int d = edst[e];
  int p = atomicAdd(&cur[d], 1);
  const float* ea = sh_ea + t * 9;
  float4 r0 = {ea[0], ea[1], ea[2], ea[3]};
  float4 r1 = {ea[4], ea[5], ea[6], ea[7]};
  float4 r2 = {ea[8], __int_as_float(esrc[e]), __int_as_float(e), 0.f};
  float4* dst = (float4*)(ed2 + (size_t)p * 12);
  dst[0] = r0; dst[1] = r1; dst[2] = r2;
  if (e < N_NODES) {
    int c = counts[e];
    int b = c < 255 ? c : 255;
    int q = atomicAdd(&dcur[b], 1);
    order[q] = e; obeg[q] = offs[e]; ocnt[q] = c;
  }
}

__device__ inline f32x4 wtile(const unsigned short* __restrict__ fc1p,
                              bf16x8 a0, bf16x8 a1, int mrow, int quad, int t) {
  f32x4 acc = {0.f, 0.f, 0.f, 0.f};
  bf16x8 b0 = *(const bf16x8*)(fc1p + ((size_t)((t * 2 + 0) * 16 + mrow) * 4 + quad) * 8);
  bf16x8 b1 = *(const bf16x8*)(fc1p + ((size_t)((t * 2 + 1) * 16 + mrow) * 4 + quad) * 8);
  acc = __builtin_amdgcn_mfma_f32_16x16x32_bf16(b0, a0, acc, 0, 0, 0);
  acc = __builtin_amdgcn_mfma_f32_16x16x32_bf16(b1, a1, acc, 0, 0, 0);
  return acc;
}

struct WgemmShared {
  __align__(16) float ele[64][8];
  __align__(16) unsigned short h[64 * 72];   // 72-stride pad
};

// STREAMING MFMA radial GEMM: 64 edges/block in ORIGINAL edge order,
// writes packed wbuf (640 B/edge). fc1p pre-scaled by K; pack via
// v_cvt_pk_bf16_f32. PK=true: h-stage uses fc0t rows (v_pk_fma).
template <bool PK>
__device__ void w_gemm_body(WgemmShared& sh, int blk,
    const float* __restrict__ eleg, const float* __restrict__ fc0,
    const float* __restrict__ fc0t,
    const unsigned short* __restrict__ fc1p, unsigned short* __restrict__ wout) {
  int t = threadIdx.x;
  int eb = blk * 64;
  if (t < 128) {
    int e = t >> 1, hh = t & 1;
    ((float4*)&sh.ele[e][0])[hh] =
        *(const float4*)(eleg + (size_t)(eb + e) * 8 + hh * 4);
  }
  __syncthreads();
  #pragma unroll
  for (int ii = 0; ii < 16; ++ii) {
    int idx = t + ii * 256;
    int e = idx >> 6, k = idx & 63;
    float acc;
    if constexpr (PK) {
      f32x2 a2 = {0.f, 0.f};
      const f32x2* er = (const f32x2*)&sh.ele[e][0];
      const f32x2* fr = (const f32x2*)(fc0t + k * 8);
      #pragma unroll
      for (int m = 0; m < 4; ++m) a2 += er[m] * fr[m];
      acc = a2.x + a2.y;
    } else {
      acc = 0.f;
      #pragma unroll
      for (int m = 0; m < 8; ++m) acc += sh.ele[e][m] * fc0[m * 64 + k];
    }
    acc *= RS8;
    float hv = SILU_C_ * acc / (1.f + __expf(-acc));
    sh.h[e * 72 + k] = f2bf(hv);
  }
  __syncthreads();

  int wv = t >> 6, lane = t & 63;
  int m0 = wv * 16;
  int mrow = lane & 15, quad = lane >> 4;
  bf16x8 a0 = *(const bf16x8*)(sh.h + (m0 + mrow) * 72 + quad * 8);
  bf16x8 a1 = *(const bf16x8*)(sh.h + (m0 + mrow) * 72 + 32 + quad * 8);
  char* wbase = (char*)wout + (size_t)(eb + m0 + mrow) * 640;
  #pragma unroll
  for (int tt = 0; tt < 4; ++tt) {
    f32x4 Av = wtile(fc1p, a0, a1, mrow, quad, tt);
    f32x4 Bv = wtile(fc1p, a0, a1, mrow, quad, tt + 4);
    uint4 st;
    st.x = cvtpk2bf(Av[0], Bv[0]);
    st.y = cvtpk2bf(Av[1], Bv[1]);
    st.z = cvtpk2bf(Av[2], Bv[2]);
    st.w = cvtpk2bf(Av[3], Bv[3]);
    *(uint4*)(wbase + 64 * tt + 16 * quad) = st;
  }
  #pragma unroll
  for (int tt = 8; tt < 12; ++tt) {
    f32x4 Cv = wtile(fc1p, a0, a1, mrow, quad, tt);
    uint2 st;
    st.x = cvtpk2bf(Cv[0], Cv[1]);
    st.y = cvtpk2bf(Cv[2], Cv[3]);
    *(uint2*)(wbase + 256 + 32 * (tt - 8) + 8 * quad) = st;
  }
  #pragma unroll
  for (int tt = 12; tt < 14; ++tt) {
    f32x4 Dv = wtile(fc1p, a0, a1, mrow, quad, tt);
    f32x4 Ev = wtile(fc1p, a0, a1, mrow, quad, tt + 2);
    f32x4 Fv = wtile(fc1p, a0, a1, mrow, quad, tt + 4);
    f32x4 Gv = wtile(fc1p, a0, a1, mrow, quad, tt + 6);
    char* db = wbase + 384 + 128 * (tt - 12) + 32 * quad;
    uint4 s0, s1;
    s0.x = cvtpk2bf(Dv[0], Ev[0]); s0.y = cvtpk2bf(Fv[0], Gv[0]);
    s0.z = cvtpk2bf(Dv[1], Ev[1]); s0.w = cvtpk2bf(Fv[1], Gv[1]);
    s1.x = cvtpk2bf(Dv[2], Ev[2]); s1.y = cvtpk2bf(Fv[2], Gv[2]);
    s1.z = cvtpk2bf(Dv[3], Ev[3]); s1.w = cvtpk2bf(Fv[3], Gv[3]);
    *(uint4*)(db) = s0;
    *(uint4*)(db + 16) = s1;
  }
}

// node_pre (split mode): k_out-style batched lin1, pk-packed dots.
#define NBK_PRE 16
__device__ void node_pre_body2(float* sh, int blk,
    const float* __restrict__ xin, const float* __restrict__ attr,
    const float* __restrict__ l1w0t, const float* __restrict__ l1w1t,
    float* __restrict__ y) {
  int t = threadIdx.x;
  int n0 = blk * NBK_PRE;
  for (int i = t; i < NBK_PRE * 160; i += 256) {
    int n = i / 160, c = i - n * 160;
    float v = xin[(size_t)(n0 + n) * 160 + c];
    int dst;
    if (c < 64) dst = c;
    else { int q = c - 64; int u = q / 3; int ii = q - u * 3; dst = 64 + ii * 32 + u; }
    sh[n * 176 + dst] = v;
  }
  if (t < NBK_PRE) sh[2816 + t] = attr[n0 + t];
  __syncthreads();
  if (t < 64) {
    const float4* wr = (const float4*)(l1w0t + t * 64);
    f32x2 a2[NBK_PRE];
    #pragma unroll
    for (int n = 0; n < NBK_PRE; ++n) a2[n] = (f32x2){0.f, 0.f};
    #pragma unroll 4
    for (int c4 = 0; c4 < 16; ++c4) {
      float4 wv = wr[c4];
      f32x2 wlo = {wv.x, wv.y}, whi = {wv.z, wv.w};
      #pragma unroll
      for (int n = 0; n < NBK_PRE; ++n) {
        float4 xv = *(const float4*)(sh + n * 176 + 4 * c4);
        f32x2 xlo = {xv.x, xv.y}, xhi = {xv.z, xv.w};
        a2[n] += xlo * wlo;
        a2[n] += xhi * whi;
      }
    }
    #pragma unroll
    for (int n = 0; n < NBK_PRE; ++n)
      y[(size_t)(n0 + n) * 192 + t] = (a2[n].x + a2[n].y) * sh[2816 + n] * 0.125f;
  } else if (t < 160) {
    int q = t - 64, v = q / 3, ii = q - v * 3;
    const float4* wr = (const float4*)(l1w1t + v * 32);
    f32x2 a2[NBK_PRE];
    #pragma unroll
    for (int n = 0; n < NBK_PRE; ++n) a2[n] = (f32x2){0.f, 0.f};
    #pragma unroll 2
    for (int c4 = 0; c4 < 8; ++c4) {
      float4 wv = wr[c4];
      f32x2 wlo = {wv.x, wv.y}, whi = {wv.z, wv.w};
      #pragma unroll
      for (int n = 0; n < NBK_PRE; ++n) {
        float4 xv = *(const float4*)(sh + n * 176 + 64 + ii * 32 + 4 * c4);
        f32x2 xlo = {xv.x, xv.y}, xhi = {xv.z, xv.w};
        a2[n] += xlo * wlo;
        a2[n] += xhi * whi;
      }
    }
    #pragma unroll
    for (int n = 0; n < NBK_PRE; ++n) {
      float r = (a2[n].x + a2[n].y) * sh[2816 + n] * RS32;
      float* yr = y + (size_t)(n0 + n) * 192 + 64 + v * 4;
      yr[ii] = r;
      if (ii == 2) yr[3] = 0.f;
    }
  }
}

// OLD node_pre (fallback only)
__device__ void node_pre_body(int blk,
    const float* __restrict__ xin, const float* __restrict__ attr,
    const float* __restrict__ l1_w0, const float* __restrict__ l1_w1,
    float* __restrict__ y) {
  int idx = blk * 256 + threadIdx.x;
  int n = idx / 160, c = idx - n * 160;
  const float* xr = xin + (size_t)n * 160;
  float a = attr[n];
  if (c < 64) {
    float y_ = 0.f;
    #pragma unroll 8
    for (int u = 0; u < 64; ++u) y_ += xr[u] * l1_w0[u * 64 + c];
    y[(size_t)n * 192 + c] = y_ * a * 0.125f;
  } else {
    int t = c - 64; int v = t / 3, i = t - v * 3;
    float y_ = 0.f;
    #pragma unroll 8
    for (int u = 0; u < 32; ++u) y_ += xr[64 + u * 3 + i] * l1_w1[u * 32 + v];
    y[(size_t)n * 192 + 64 + v * 4 + i] = y_ * a * RS32;
    if (i == 2) y[(size_t)n * 192 + 64 + v * 4 + 3] = 0.f;
  }
}

// big fused mid-stage (launched right after k_init; no perm dependency):
// block 0            = scan (hidden under w_gemm)
// blocks [1,2501)    = w_gemm (original edge order)
// PRE2=true : [2501,3126) = node_pre_body2
// PRE2=false: [2501,8751) = old node_pre
template <bool PRE2>
__global__ __launch_bounds__(256) void k_big(
    const float* __restrict__ eleg, const float* __restrict__ fc0,
    const unsigned short* __restrict__ fc1p, unsigned short* __restrict__ wout,
    const float* __restrict__ xin, const float* __restrict__ attr,
    const float* __restrict__ l1_w0, const float* __restrict__ l1_w1,
    const float* __restrict__ l1w0t, const float* __restrict__ l1w1t,
    const float* __restrict__ fc0t, float* __restrict__ y,
    const int* __restrict__ counts, int* __restrict__ offs,
    int* __restrict__ cur, int* __restrict__ dcur) {
  __shared__ __align__(16) char shraw[11328];
  if (blockIdx.x == 0) {
    scan_body(shraw, counts, offs, cur, dcur);
  } else if (blockIdx.x <= 2500) {
    w_gemm_body<PRE2>(*(WgemmShared*)shraw, blockIdx.x - 1, eleg, fc0, fc0t, fc1p, wout);
  } else if (PRE2) {
    node_pre_body2((float*)shraw, blockIdx.x - 2501, xin, attr, l1w0t, l1w1t, y);
  } else {
    node_pre_body(blockIdx.x - 2501, xin, attr, l1_w0, l1_w1, y);
  }
}

// node_agg: 2500 blocks x 4 waves, ONE NODE PER WAVE in degree-desc order.
// Edge rows / V-load bases are WAVE-UNIFORM -> readfirstlane scalarization:
// ed2 row via s_load (SMEM pipe, zero VALU), y/wbuf base addressing in SALU;
// only the per-lane-offset loads stay vector. E/V two-slot pipeline.
// EPI=true : bank-padded component-major LDS epilogue (0 conflicts),
//            weight float4 reused over 4 nodes, pk-packed dots (R7 verified).
// EPI=false: original per-wave fused epilogue (small-ws fallback).
#define WREG 960
template <bool EPI>
__global__ __launch_bounds__(256) void node_agg(
    const float* __restrict__ y, const float* __restrict__ xin,
    const float* __restrict__ attr, const float* __restrict__ ed2,
    const unsigned short* __restrict__ wbuf,
    const int* __restrict__ order, const int* __restrict__ obeg,
    const int* __restrict__ ocnt,
    const float* __restrict__ sc_w0, const float* __restrict__ sc_w1,
    const float* __restrict__ w0, const float* __restrict__ w1,
    const float* __restrict__ w2, float* __restrict__ out,
    const float* __restrict__ wt) {
  int tid = threadIdx.x, wid = tid >> 6, lane = tid & 63, l31 = lane & 31;
  int gw = blockIdx.x * 4 + wid;
  // fixed per-lane byte offsets (loop-invariant)
  int voY  = 4 * lane;           // y scalar block
  int voX  = 256 + 16 * l31;     // y vector float4 {x0,x1,x2,0}
  int voAB = 4 * lane;           // wbuf AB
  int voC  = 256 + 2 * lane;     // wbuf C
  int voDG = 384 + 8 * l31;      // wbuf DEFG

#define E_LOAD(S, idx)                                                         \
  if ((idx) < cnt) {                                                           \
    int ro_ = __builtin_amdgcn_readfirstlane(beg + (idx));                     \
    const float4* ep = (const float4*)(ed2 + (size_t)ro_ * 12);                \
    PE0##S = ep[0]; PE1##S = ep[1]; PE2##S = ep[2];                            \
  }
#define V_LOAD(S, idx)                                                         \
  if ((idx) < cnt) {                                                           \
    int srcn = __builtin_amdgcn_readfirstlane(__float_as_int(PE2##S.y));       \
    int eorg = __builtin_amdgcn_readfirstlane(__float_as_int(PE2##S.z));       \
    const char* yb = (const char*)y + (size_t)srcn * 768;                      \
    Y##S = *(const float*)(yb + voY);                                          \
    X##S = *(const f32x4*)(yb + voX);                                          \
    const char* wb = (const char*)wbuf + (size_t)eorg * 640;                   \
    AB##S = *(const unsigned*)(wb + voAB);                                     \
    Cw##S = *(const unsigned short*)(wb + voC);                                \
    DG##S = *(const uint2*)(wb + voDG);                                        \
  }
#define COMPUTE(S)                                                             \
  {                                                                            \
    float e0 = PE0##S.x, ey = PE0##S.y, ez = PE0##S.z, ex = PE0##S.w;          \
    float q0 = PE1##S.x, q1 = PE1##S.y, q2 = PE1##S.z, q3 = PE1##S.w;          \
    float q4 = PE2##S.x;                                                       \
    float Yv = Y##S, x0 = X##S.x, x1 = X##S.y, x2 = X##S.z;                    \
    float vA = bf2f(AB##S), vB = bfhi(AB##S), vC = bf2f(Cw##S);                \
    float vD = bf2f(DG##S.x), vE = bfhi(DG##S.x);                              \
    float vF = bf2f(DG##S.y), vG = bfhi(DG##S.y);                              \
    aK0 += Yv * e0 * vA;                                                       \
    float tB = Yv * vB; aK2x += tB * ey; aK2y += tB * ez; aK2z += tB * ex;     \
    float tC = Yv * vC;                                                        \
    aK5a += tC * q0; aK5b += tC * q1; aK5c += tC * q2;                         \
    aK5d += tC * q3; aK5e += tC * q4;                                          \
    float t1 = x0 * ey + x1 * ez + x2 * ex; aK1 += (RS3 * vE) * t1;            \
    float s3 = e0 * vD; aK3x += x0 * s3; aK3y += x1 * s3; aK3z += x2 * s3;     \
    float s4 = SQ3_ * vG;                                                      \
    aK4x += s4 * (B_ * (x2 * q0 + x1 * q1 - x0 * q4) - A_ * x0 * q2);          \
    aK4y += s4 * (B_ * (x0 * q1 + x2 * q3) + 2.f * A_ * x1 * q2);              \
    aK4z += s4 * (B_ * (x0 * q0 + x1 * q3 + x2 * q4) - A_ * x2 * q2);          \
    float s6 = SQ5_ * vF;                                                      \
    aK6a += s6 * (-B_ * (x0 * ex + x2 * ey));                                  \
    aK6b += s6 * (-B_ * (x0 * ez + x1 * ey));                                  \
    aK6c += s6 * ( A_ * (x0 * ey + x2 * ex - 2.f * x1 * ez));                  \
    aK6d += s6 * (-B_ * (x1 * ex + x2 * ez));                                  \
    aK6e += s6 * ( B_ * (x0 * ey - x2 * ex));                                  \
  }
#define LWAIT __asm__ volatile("s_waitcnt lgkmcnt(0)" ::: "memory")

  int n = order[gw], beg = obeg[gw], cnt = ocnt[gw];

  float aK0 = 0.f, aK2x = 0.f, aK2y = 0.f, aK2z = 0.f;
  float aK5a = 0.f, aK5b = 0.f, aK5c = 0.f, aK5d = 0.f, aK5e = 0.f;
  float aK1 = 0.f, aK3x = 0.f, aK3y = 0.f, aK3z = 0.f;
  float aK4x = 0.f, aK4y = 0.f, aK4z = 0.f;
  float aK6a = 0.f, aK6b = 0.f, aK6c = 0.f, aK6d = 0.f, aK6e = 0.f;

  float4 PE0a, PE1a, PE2a, PE0b, PE1b, PE2b;
  float Ya, Yb; f32x4 Xa, Xb;
  unsigned ABa, ABb; unsigned short Cwa, Cwb;
  uint2 DGa, DGb;

  E_LOAD(a, 0)
  E_LOAD(b, 1)
  V_LOAD(a, 0)

  int i = 0;
  while (i < cnt) {
    V_LOAD(b, i + 1)
    COMPUTE(a)
    E_LOAD(a, i + 2)
    ++i; if (i >= cnt) break;
    V_LOAD(a, i + 1)
    COMPUTE(b)
    E_LOAD(b, i + 2)
    ++i;
  }

  if constexpr (EPI) {
    // per-node layout (floats, node stride 1152):
    //   R[0,984)  bank-padded: m0@0 (96), m1@96 stride 132, m2@488 stride 100
    //   xin[984,1144), pad[1144,1152)
    // meta: attr @4608+wid, nid @int 4612+wid
    __shared__ __align__(16) float sepi[4 * 1152 + 8];
    float* R = sepi + wid * 1152;
    R[lane]        = aK0  * QDEG;   // m0 u=lane          (k0)
    R[96 + lane]   = aK2x * QDEG;   // m1 ii=0 u=lane     (k2)
    R[228 + lane]  = aK2y * QDEG;   // m1 ii=1
    R[360 + lane]  = aK2z * QDEG;   // m1 ii=2
    R[488 + lane]  = aK5a * QDEG;   // m2 kk=0 u=lane     (k5)
    R[588 + lane]  = aK5b * QDEG;
    R[688 + lane]  = aK5c * QDEG;
    R[788 + lane]  = aK5d * QDEG;
    R[888 + lane]  = aK5e * QDEG;
    if (lane < 32) {
      R[64 + lane]   = aK1  * QDEG; // m0 u=64+lane       (k1)
      R[160 + lane]  = aK3x * QDEG; // m1 ii=0 u=64+lane  (k3)
      R[292 + lane]  = aK3y * QDEG;
      R[424 + lane]  = aK3z * QDEG;
      R[192 + lane]  = aK4x * QDEG; // m1 ii=0 u=96+lane  (k4)
      R[324 + lane]  = aK4y * QDEG;
      R[456 + lane]  = aK4z * QDEG;
      R[552 + lane]  = aK6a * QDEG; // m2 kk=0 u=64+lane  (k6)
      R[652 + lane]  = aK6b * QDEG;
      R[752 + lane]  = aK6c * QDEG;
      R[852 + lane]  = aK6d * QDEG;
      R[952 + lane]  = aK6e * QDEG;
    }
    if (lane < 40)
      *(float4*)(sepi + wid * 1152 + 984 + 4 * lane) =
          *(const float4*)(xin + (size_t)n * 160 + 4 * lane);
    if (lane == 40) sepi[4608 + wid] = attr[n];
    if (lane == 41) ((int*)sepi)[4612 + wid] = n;
    __syncthreads();
    const float* w0t  = wt;
    const float* sw0t = wt + 6144;
    const float* w1t  = wt + 10240;
    const float* w2t  = wt + 14336;
    const float* sw1t = wt + 17408;
    for (int pass = 0; pass < 2; ++pass) {
      if (pass == 1 && tid >= 64) break;
      int ch = pass == 0 ? tid : 256 + tid;
      f32x2 a2[4];
      float accs[4] = {0.f, 0.f, 0.f, 0.f};
      f32x2 s2[4];
      #pragma unroll
      for (int k = 0; k < 4; ++k) { a2[k] = (f32x2){0.f, 0.f}; s2[k] = (f32x2){0.f, 0.f}; }
      if (ch < 64) {
        const float4* wr  = (const float4*)(w0t + ch * 96);
        const float4* swr = (const float4*)(sw0t + ch * 64);
        #pragma unroll 4
        for (int c = 0; c < 24; ++c) {
          float4 wv = wr[c];
          f32x2 wlo = {wv.x, wv.y}, whi = {wv.z, wv.w};
          #pragma unroll
          for (int k = 0; k < 4; ++k) {
            float4 rv = *(const float4*)(sepi + k * 1152 + 4 * c);
            f32x2 rlo = {rv.x, rv.y}, rhi = {rv.z, rv.w};
            a2[k] += rlo * wlo;
            a2[k] += rhi * whi;
          }
        }
        #pragma unroll 4
        for (int c = 0; c < 16; ++c) {
          float4 wv = swr[c];
          f32x2 wlo = {wv.x, wv.y}, whi = {wv.z, wv.w};
          #pragma unroll
          for (int k = 0; k < 4; ++k) {
            float4 xv = *(const float4*)(sepi + k * 1152 + 984 + 4 * c);
            f32x2 xlo = {xv.x, xv.y}, xhi = {xv.z, xv.w};
            s2[k] += xlo * wlo;
            s2[k] += xhi * whi;
          }
        }
        #pragma unroll
        for (int k = 0; k < 4; ++k) {
          float a = sepi[4608 + k]; int nid = ((const int*)sepi)[4612 + k];
          float o = a2[k].x + a2[k].y, sv = s2[k].x + s2[k].y;
          out[(size_t)nid * 320 + ch] =
              CS_ * (sv * a * 0.125f) + CX_ * (o * a * RS96);
        }
      } else if (ch < 160) {
        int q = ch - 64, v = q / 3, ii = q - v * 3;
        const float4* wr = (const float4*)(w1t + v * 128);
        #pragma unroll 4
        for (int c = 0; c < 32; ++c) {
          float4 wv = wr[c];
          f32x2 wlo = {wv.x, wv.y}, whi = {wv.z, wv.w};
          #pragma unroll
          for (int k = 0; k < 4; ++k) {
            float4 rv = *(const float4*)(sepi + k * 1152 + 96 + ii * 132 + 4 * c);
            f32x2 rlo = {rv.x, rv.y}, rhi = {rv.z, rv.w};
            a2[k] += rlo * wlo;
            a2[k] += rhi * whi;
          }
        }
        for (int u = 0; u < 32; ++u) {
          float wv = sw1t[v * 32 + u];
          #pragma unroll
          for (int k = 0; k < 4; ++k)
            accs[k] += sepi[k * 1152 + 984 + 64 + 3 * u + ii] * wv;
        }
        #pragma unroll
        for (int k = 0; k < 4; ++k) {
          float a = sepi[4608 + k]; int nid = ((const int*)sepi)[4612 + k];
          float o = a2[k].x + a2[k].y;
          out[(size_t)nid * 320 + ch] =
              CS_ * (accs[k] * a * RS32) + CX_ * (o * a * RS128);
        }
      } else {
        int q = ch - 160, v = q / 5, kk = q - v * 5;
        const float4* wr = (const float4*)(w2t + v * 96);
        #pragma unroll 4
        for (int c = 0; c < 24; ++c) {
          float4 wv = wr[c];
          f32x2 wlo = {wv.x, wv.y}, whi = {wv.z, wv.w};
          #pragma unroll
          for (int k = 0; k < 4; ++k) {
            float4 rv = *(const float4*)(sepi + k * 1152 + 488 + kk * 100 + 4 * c);
            f32x2 rlo = {rv.x, rv.y}, rhi = {rv.z, rv.w};
            a2[k] += rlo * wlo;
            a2[k] += rhi * whi;
          }
        }
        #pragma unroll
        for (int k = 0; k < 4; ++k) {
          float a = sepi[4608 + k]; int nid = ((const int*)sepi)[4612 + k];
          float o = a2[k].x + a2[k].y;
          out[(size_t)nid * 320 + ch] = o * a * RS96;
        }
      }
    }
  } else {
    // fallback: original fused epilogue
    __shared__ __align__(16) float smem[4 * WREG];
    float* R = smem + wid * WREG;
    R[lane]            = aK0  * QDEG;
    R[96 + 3 * lane]   = aK2x * QDEG;
    R[97 + 3 * lane]   = aK2y * QDEG;
    R[98 + 3 * lane]   = aK2z * QDEG;
    R[480 + 5 * lane]  = aK5a * QDEG;
    R[481 + 5 * lane]  = aK5b * QDEG;
    R[482 + 5 * lane]  = aK5c * QDEG;
    R[483 + 5 * lane]  = aK5d * QDEG;
    R[484 + 5 * lane]  = aK5e * QDEG;
    if (lane < 32) {
      R[64 + lane]       = aK1  * QDEG;
      R[288 + 3 * lane]  = aK3x * QDEG;
      R[289 + 3 * lane]  = aK3y * QDEG;
      R[290 + 3 * lane]  = aK3z * QDEG;
      R[384 + 3 * lane]  = aK4x * QDEG;
      R[385 + 3 * lane]  = aK4y * QDEG;
      R[386 + 3 * lane]  = aK4z * QDEG;
      R[800 + 5 * lane]  = aK6a * QDEG;
      R[801 + 5 * lane]  = aK6b * QDEG;
      R[802 + 5 * lane]  = aK6c * QDEG;
      R[803 + 5 * lane]  = aK6d * QDEG;
      R[804 + 5 * lane]  = aK6e * QDEG;
    }
    LWAIT;
    float a = attr[n];
    const float* xr = xin + (size_t)n * 160;
    float* orow = out + (size_t)n * 320;
    #pragma unroll
    for (int jo = 0; jo < 5; ++jo) {
      int oc = lane + 64 * jo;
      float res;
      if (oc < 64) {
        float o = 0.f, sv = 0.f;
        #pragma unroll 8
        for (int u = 0; u < 96; ++u) o += R[u] * w0[u * 64 + oc];
        #pragma unroll 8
        for (int u = 0; u < 64; ++u) sv += xr[u] * sc_w0[u * 64 + oc];
        res = CS_ * (sv * a * 0.125f) + CX_ * (o * a * RS96);
      } else if (oc < 160) {
        int t2 = oc - 64, v = t2 / 3, ii = t2 - v * 3;
        float o = 0.f, sv = 0.f;
        #pragma unroll 8
        for (int u = 0; u < 128; ++u) o += R[96 + u * 3 + ii] * w1[u * 32 + v];
        #pragma unroll 8
        for (int u = 0; u < 32; ++u) sv += xr[64 + u * 3 + ii] * sc_w1[u * 32 + v];
        res = CS_ * (sv * a * RS32) + CX_ * (o * a * RS128);
      } else {
        int t2 = oc - 160, v = t2 / 5, kk = t2 - v * 5;
        float o = 0.f;
        #pragma unroll 8
        for (int u = 0; u < 96; ++u) o += R[480 + u * 5 + kk] * w2[u * 32 + v];
        res = o * a * RS96;
      }
      orow[oc] = res;
    }
  }
#undef E_LOAD
#undef V_LOAD
#undef COMPUTE
#undef LWAIT
}

extern "C" void kernel_launch(void* const* d_in, const int* in_sizes, int n_in,
                              void* d_out, int out_size, void* d_ws, size_t ws_size,
                              hipStream_t stream) {
  const float* node_input = (const float*)d_in[0];
  const float* node_attr  = (const float*)d_in[1];
  const int*   edge_src   = (const int*)d_in[2];
  const int*   edge_dst   = (const int*)d_in[3];
  const float* edge_attr  = (const float*)d_in[4];
  const float* ele        = (const float*)d_in[5];
  const float* sc_w0      = (const float*)d_in[6];
  const float* sc_w1      = (const float*)d_in[7];
  const float* l1_w0      = (const float*)d_in[8];
  const float* l1_w1      = (const float*)d_in[9];
  const float* fc_w0      = (const float*)d_in[10];
  const float* fc_w1      = (const float*)d_in[11];
  const float* l2_w0      = (const float*)d_in[12];
  const float* l2_w1      = (const float*)d_in[13];
  const float* l2_w2      = (const float*)d_in[14];
  float* out = (float*)d_out;

  char* base = (char*)d_ws;
  float* y              = (float*)(base);                       // 7.68 MB (stride 192)
  unsigned short* wbuf  = (unsigned short*)(base + 7680000);    // 102.4 MB packed (orig order)
  float* ed2            = (float*)(base + 110080000);           // 7.68 MB (stride 12)
  int* counts           = (int*)(base + 122880000);
  int* offs             = (int*)(base + 122920000);
  int* cur              = (int*)(base + 122960000);
  int* order            = (int*)(base + 123000000);
  int* obeg             = (int*)(base + 123040000);
  int* ocnt             = (int*)(base + 123080000);
  int* dcur             = (int*)(base + 123120000);             // 1 KB
  unsigned short* fc1p  = (unsigned short*)(base + 123121024);  // 40 KB
  float* wt             = (float*)(base + 123161984);           // 73,728 B transposed lin2/sc
  float* l1t            = (float*)(base + 123235712);           // 22,528 B lin1t + fc0t

  // EPI mode needs ws through l1t end = 123,235,712 + 22,528
  const bool epi = ws_size >= (size_t)123258240;

  hipMemsetAsync(counts, 0, N_NODES * sizeof(int), stream);
  hipLaunchKernelGGL(k_init, dim3(176), dim3(256), 0, stream, edge_dst, counts,
                     fc_w1, fc1p,
                     l2_w0, sc_w0, l2_w1, l2_w2, sc_w1, epi ? wt : (float*)nullptr,
                     l1_w0, l1_w1, fc_w0, epi ? l1t : (float*)nullptr);
  if (epi) {
    hipLaunchKernelGGL(HIP_KERNEL_NAME(k_big<true>), dim3(1 + 2500 + 625), dim3(256), 0,
                       stream, ele, fc_w0, fc1p, wbuf,
                       node_input, node_attr, l1_w0, l1_w1, l1t, l1t + 4096,
                       l1t + 5120, y, counts, offs, cur, dcur);
    hipLaunchKernelGGL(k_perm, dim3(N_EDGES / 256), dim3(256), 0, stream,
                       edge_dst, cur, counts, offs, dcur, order, obeg, ocnt,
                       edge_attr, edge_src, ed2);
    hipLaunchKernelGGL(HIP_KERNEL_NAME(node_agg<true>), dim3(2500), dim3(256), 0, stream,
                       y, node_input, node_attr, ed2, wbuf,
                       order, obeg, ocnt, sc_w0, sc_w1, l2_w0, l2_w1, l2_w2, out, wt);
  } else {
    hipLaunchKernelGGL(HIP_KERNEL_NAME(k_big<false>), dim3(1 + 2500 + 6250), dim3(256), 0,
                       stream, ele, fc_w0, fc1p, wbuf,
                       node_input, node_attr, l1_w0, l1_w1,
                       (float*)nullptr, (float*)nullptr, (float*)nullptr, y,
                       counts, offs, cur, dcur);
    hipLaunchKernelGGL(k_perm, dim3(N_EDGES / 256), dim3(256), 0, stream,
                       edge_dst, cur, counts, offs, dcur, order, obeg, ocnt,
                       edge_attr, edge_src, ed2);
    hipLaunchKernelGGL(HIP_KERNEL_NAME(node_agg<false>), dim3(2500), dim3(256), 0, stream,
                       y, node_input, node_attr, ed2, wbuf,
                       order, obeg, ocnt, sc_w0, sc_w1, l2_w0, l2_w1, l2_w2, out,
                       (float*)nullptr);
  }
}